// Round 16
// baseline (268.387 us; speedup 1.0000x reference)
//
#include <hip/hip_runtime.h>
#include <hip/hip_bf16.h>
#include <math.h>

#define NN 10000
#define EE 160000
#define CSZ 128
#define NVB (EE/256)   // 625 V-blocks, then 625 K-blocks

#define INV_S8  0.35355339059327373f   // 1/sqrt(8)
#define INV_S32 0.17677669529663687f   // 1/sqrt(32)
#define INV_S2  0.7071067811865476f    // 1/sqrt(2)
#define INV_S3  0.5773502691896258f    // 1/sqrt(3)

typedef short s16x8 __attribute__((ext_vector_type(8)));
typedef float f32x4 __attribute__((ext_vector_type(4)));

__device__ __forceinline__ unsigned short f2bf(float f){
  __hip_bfloat16 h = __float2bfloat16(f);
  return *reinterpret_cast<unsigned short*>(&h);
}

// ---------------- Fused node kernel: f0/f1 GEMM + rotate + gs/gv/qs/qv -----
__global__ __launch_bounds__(192) void k_node(
    const float* __restrict__ frame,
    const float* __restrict__ Wf0, const float* __restrict__ bf0,
    const float* __restrict__ Wf1, const float* __restrict__ bf1,
    const float* __restrict__ rot, const float* __restrict__ trans,
    const float* __restrict__ tfn,
    const float* __restrict__ Wgs, const float* __restrict__ Wgv,
    const float* __restrict__ Wqs, const float* __restrict__ Wqv,
    float* __restrict__ Gs, float* __restrict__ Gv,
    float* __restrict__ Qs, float* __restrict__ Qv){
  __shared__ float ff[160];
  __shared__ float f1r[32][3];
  int n = blockIdx.x;
  int t = threadIdx.x;
  if(t < 160){
    bool is0 = t < 64;
    int cc = is0 ? t : (t-64);
    const float* W = is0 ? Wf0 : Wf1;
    int ldw = is0 ? 64 : 96;
    float acc = is0 ? bf0[cc] : bf1[cc];
    const float* fp = frame + (size_t)n*CSZ;
    #pragma unroll 8
    for(int k=0;k<CSZ;k++)
      acc = fmaf(fp[k], W[k*ldw + cc], acc);
    ff[t] = acc;
  }
  __syncthreads();
  if(t < 32){
    float v0 = ff[64+t*3+0], v1 = ff[64+t*3+1], v2 = ff[64+t*3+2];
    const float* R = rot + (size_t)n*9;
    const float* tr = trans + (size_t)n*3;
    f1r[t][0] = R[0]*v0 + R[1]*v1 + R[2]*v2 + tr[0];
    f1r[t][1] = R[3]*v0 + R[4]*v1 + R[5]*v2 + tr[1];
    f1r[t][2] = R[6]*v0 + R[7]*v1 + R[8]*v2 + tr[2];
  }
  __syncthreads();
  if(t < 16){
    float a = 0.f;
    #pragma unroll
    for(int u=0;u<64;u++) a = fmaf(ff[u], Wgs[u*16+t], a);
    Gs[(size_t)n*16+t] = a * 0.125f;
  } else if(t < 40){
    int idx = t-16, w = idx/3, i = idx%3; float a = 0.f;
    #pragma unroll
    for(int u=0;u<32;u++) a = fmaf(f1r[u][i], Wgv[u*8+w], a);
    Gv[(size_t)n*24+idx] = a * INV_S32;
  } else if(t < 56){
    int w = t-40; float a = 0.f;
    #pragma unroll
    for(int u=0;u<16;u++) a = fmaf(tfn[(size_t)n*40+u], Wqs[u*16+w], a);
    Qs[(size_t)n*16+w] = a * 0.25f;
  } else if(t < 80){
    int idx = t-56, w = idx/3, i = idx%3; float a = 0.f;
    #pragma unroll
    for(int u=0;u<8;u++) a = fmaf(tfn[(size_t)n*40+16+u*3+i], Wqv[u*8+w], a);
    Qv[(size_t)n*24+idx] = a * INV_S8;
  }
}

// ---------------- CSR build ------------------------------------------------
__global__ __launch_bounds__(256) void k_hist(const int* __restrict__ ei, int* __restrict__ cnt){
  int e = blockIdx.x*256 + threadIdx.x;
  if(e < EE) atomicAdd(&cnt[ei[EE + e]], 1);
}

__global__ __launch_bounds__(256) void k_scan(const int* __restrict__ cnt,
                                              int* __restrict__ ofs, int* __restrict__ fill){
  __shared__ int tsum[256];
  int t = threadIdx.x;
  const int CH = (NN + 255)/256;
  int base = t*CH;
  int s = 0;
  for(int i=0;i<CH;i++){ int idx=base+i; if(idx<NN) s += cnt[idx]; }
  tsum[t] = s;
  __syncthreads();
  for(int off=1; off<256; off<<=1){
    int v = (t>=off)? tsum[t-off] : 0;
    __syncthreads();
    tsum[t] += v;
    __syncthreads();
  }
  int run = (t==0)? 0 : tsum[t-1];
  for(int i=0;i<CH;i++){
    int idx = base+i;
    if(idx < NN){ ofs[idx] = run; fill[idx] = run; run += cnt[idx]; }
  }
  if(t==255) ofs[NN] = tsum[255];
}

__global__ __launch_bounds__(256) void k_scatter(const int* __restrict__ ei,
                                                 int* __restrict__ fill, int* __restrict__ elist){
  int e = blockIdx.x*256 + threadIdx.x;
  if(e >= EE) return;
  int src = ei[EE + e];
  int pos = atomicAdd(&fill[src], 1);
  elist[pos] = e;
}

// ---------------- Weight reshape: W2 -> MFMA A-fragment order, bf16 --------
__global__ __launch_bounds__(256) void k_prepw(
    const float* __restrict__ Wk2, const float* __restrict__ bk2,
    const float* __restrict__ Wv2, const float* __restrict__ bv2,
    unsigned short* __restrict__ A2rK, unsigned short* __restrict__ A2rV,
    float* __restrict__ biasK, float* __restrict__ biasV){
  int tid = blockIdx.x*256 + threadIdx.x;
  const int NV = 896*32, NK = 640*32;
  if(tid < NV){
    int c = tid>>5, h = tid&31;
    float s = (c<384)? INV_S2 : INV_S3;
    A2rV[(c>>4)*512 + (c&15)*32 + h] = f2bf(Wv2[h*896+c]*s);
  } else if(tid < NV+NK){
    int i = tid - NV; int c = i>>5, h = i&31;
    float s = (c<384)? INV_S2 : INV_S3;
    A2rK[(c>>4)*512 + (c&15)*32 + h] = f2bf(Wk2[h*640+c]*s);
  } else if(tid < NV+NK+896){
    int c = tid - (NV+NK);
    biasV[c] = bv2[c] * ((c<384)? INV_S2 : INV_S3);
  } else if(tid < NV+NK+896+640){
    int c = tid - (NV+NK+896);
    biasK[c] = bk2[c] * ((c<384)? INV_S2 : INV_S3);
  }
}

// hidden MLP -> LDS fragments -> af[4] regs (B-operand frags). hL overlays F.
#define HID_TO_FRAGS(W1, b1) { \
  unsigned short* hL = (unsigned short*)&F[0][0]; \
  float efv[32]; \
  const float4* efp = (const float4*)(ef + (size_t)e*32); \
  _Pragma("unroll") \
  for(int q=0;q<8;q++){ float4 t=efp[q]; efv[q*4]=t.x; efv[q*4+1]=t.y; efv[q*4+2]=t.z; efv[q*4+3]=t.w; } \
  float hd[32]; \
  _Pragma("unroll") \
  for(int h=0;h<32;h++) hd[h] = b1[h]; \
  _Pragma("unroll") \
  for(int k=0;k<32;k++){ \
    float ekv = efv[k]; \
    _Pragma("unroll") \
    for(int h=0;h<32;h++) hd[h] = fmaf(ekv, W1[k*32+h], hd[h]); \
  } \
  _Pragma("unroll") \
  for(int gg=0;gg<4;gg++){ \
    s16x8 p; \
    _Pragma("unroll") \
    for(int j=0;j<8;j++) p[j] = (short)f2bf(fmaxf(hd[gg*8+j], 0.f)); \
    *(s16x8*)&hL[((g*4+gg)*16 + e16)*8] = p; \
  } \
  _Pragma("unroll") \
  for(int tt=0;tt<4;tt++) \
    af[tt] = *(const s16x8*)&hL[((tt*4 + g)*16 + e16)*8]; }

// features -> LDS (rows 0..15 fsn=Gs*0.25, rows 16..39 fv) + sh via shfl
#define STAGE_FEATURES() { \
  const float4* g4 = (const float4*)(Gs + (size_t)dst*16); \
  _Pragma("unroll") \
  for(int q=0;q<4;q++){ float4 t = g4[q]; \
    F[q*4+0][lane]=t.x*0.25f; F[q*4+1][lane]=t.y*0.25f; \
    F[q*4+2][lane]=t.z*0.25f; F[q*4+3][lane]=t.w*0.25f; } \
  const float4* v4 = (const float4*)(Gv + (size_t)dst*24); \
  _Pragma("unroll") \
  for(int q=0;q<6;q++){ float4 t = v4[q]; \
    F[16+q*4+0][lane]=t.x; F[16+q*4+1][lane]=t.y; \
    F[16+q*4+2][lane]=t.z; F[16+q*4+3][lane]=t.w; } \
  _Pragma("unroll") \
  for(int tt=0;tt<4;tt++){ \
    int sl = tt*16 + e16; \
    shs_t[tt]  = __shfl(shs, sl); \
    sv_t[tt][0]= __shfl(sv0, sl); \
    sv_t[tt][1]= __shfl(sv1, sl); \
    sv_t[tt][2]= __shfl(sv2, sl); \
    shsI8_t[tt]= shs_t[tt]*INV_S8; \
  } }

// stage helpers: chunk = 4 ntiles = 4096 B weights + 64 floats bias.
// 256 threads: thread t loads 16 B of weights; t<64 loads 1 bias float.
#define STAGE_ISSUE(A2r, bias, C0) do{ \
  wreg = *(const float4*)((const char*)(A2r) + (size_t)(C0)*1024 + (size_t)threadIdx.x*16); \
  if(threadIdx.x < 64) breg = (bias)[(C0)*16 + threadIdx.x]; \
}while(0)

#define STAGE_WRITE(WB, BB) do{ \
  *(float4*)((char*)(WB) + (size_t)threadIdx.x*16) = wreg; \
  if(threadIdx.x < 64) (BB)[threadIdx.x] = breg; \
}while(0)

// LDS-staged, double-buffered chunk pipeline. APPLY uses `ntile`, acc4[tt].
#define LDS_PIPE(A2r, bias, FIRST, LAST, ...) { \
  float4 wreg; float breg = 0.f; \
  STAGE_ISSUE(A2r, bias, FIRST); \
  STAGE_WRITE(wbuf[0], bbuf[0]); \
  __syncthreads(); \
  int cur = 0; \
  _Pragma("unroll 1") \
  for(int c0=(FIRST); c0<(LAST); c0+=4){ \
    bool more = (c0+4) < (LAST); \
    if(more){ STAGE_ISSUE(A2r, bias, c0+4); } \
    const unsigned short* wb = wbuf[cur]; \
    const float* bb = bbuf[cur]; \
    _Pragma("unroll") \
    for(int nt=0; nt<4; ++nt){ \
      int ntile = c0 + nt; \
      s16x8 Aw = *(const s16x8*)&wb[nt*512 + e16*32 + g*8]; \
      float4 b4 = *(const float4*)&bb[nt*16 + g*4]; \
      f32x4 acc4[4]; \
      _Pragma("unroll") \
      for(int tt=0; tt<4; ++tt){ \
        f32x4 a0 = {b4.x, b4.y, b4.z, b4.w}; \
        acc4[tt] = __builtin_amdgcn_mfma_f32_16x16x32_bf16(Aw, af[tt], a0, 0, 0, 0); \
      } \
      __VA_ARGS__ \
    } \
    if(more){ STAGE_WRITE(wbuf[cur^1], bbuf[cur^1]); } \
    __syncthreads(); \
    cur ^= 1; \
  } }

// ---------------- Edge V body: LDS-staged weights ---------------------------
__device__ __forceinline__ void edge_v_body(
    int blk, float (*F)[64],
    unsigned short (*wbuf)[2048], float (*bbuf)[64],
    const int* __restrict__ ei, const float* __restrict__ esh,
    const float* __restrict__ ef,
    const float* __restrict__ Gs, const float* __restrict__ Gv,
    const float* __restrict__ Wv1, const float* __restrict__ bv1,
    const unsigned short* __restrict__ A2rV, const float* __restrict__ biasV,
    float* __restrict__ EdgeV){
  int wave = threadIdx.x >> 6, lane = threadIdx.x & 63;
  int ebase = blk*256 + wave*64;
  int e = ebase + lane;
  int e16 = lane & 15, g = lane >> 4;

  int dst = ei[e];
  float4 sh4 = *(const float4*)(esh + (size_t)e*4);
  float shs = sh4.x, sv0 = sh4.y, sv1 = sh4.z, sv2 = sh4.w;

  s16x8 af[4];
  HID_TO_FRAGS(Wv1, bv1);
  float shs_t[4], sv_t[4][3], shsI8_t[4];
  STAGE_FEATURES();

  // ---- paths A+B: ntiles 0..23 -> scalar outputs A16 ----
  float A16[4][4] = {};
  LDS_PIPE(A2rV, biasV, 0, 16,
    _Pragma("unroll")
    for(int tt=0; tt<4; ++tt){
      float f = F[ntile][tt*16+e16] * shs_t[tt];
      _Pragma("unroll")
      for(int r=0;r<4;r++) A16[tt][r] = fmaf(f, acc4[tt][r], A16[tt][r]);
    }
  );
  LDS_PIPE(A2rV, biasV, 16, 24,
    int u3 = 16 + (ntile-16)*3;
    _Pragma("unroll")
    for(int tt=0; tt<4; ++tt){
      int eL = tt*16+e16;
      float f = (F[u3+0][eL]*sv_t[tt][0] + F[u3+1][eL]*sv_t[tt][1]
               + F[u3+2][eL]*sv_t[tt][2]) * INV_S8;
      _Pragma("unroll")
      for(int r=0;r<4;r++) A16[tt][r] = fmaf(f, acc4[tt][r], A16[tt][r]);
    }
  );
  #pragma unroll
  for(int tt=0; tt<4; ++tt){
    int eo = ebase + tt*16 + e16;
    *(float4*)(EdgeV + (size_t)eo*64 + g*4) =
        make_float4(A16[tt][0], A16[tt][1], A16[tt][2], A16[tt][3]);
  }

  // ---- paths C+D+E: ntiles 24..55 -> vector outputs VV ----
  float VV[4][4][3] = {};
  LDS_PIPE(A2rV, biasV, 24, 40,                // path C
    _Pragma("unroll")
    for(int tt=0; tt<4; ++tt){
      float f = F[ntile-24][tt*16+e16];
      _Pragma("unroll")
      for(int r=0;r<4;r++){
        float c = f*acc4[tt][r];
        VV[tt][r][0] = fmaf(c, sv_t[tt][0], VV[tt][r][0]);
        VV[tt][r][1] = fmaf(c, sv_t[tt][1], VV[tt][r][1]);
        VV[tt][r][2] = fmaf(c, sv_t[tt][2], VV[tt][r][2]);
      }
    }
  );
  LDS_PIPE(A2rV, biasV, 40, 48,                // path D
    int u3 = 16 + (ntile-40)*3;
    _Pragma("unroll")
    for(int tt=0; tt<4; ++tt){
      int eL = tt*16+e16;
      float f0 = F[u3+0][eL]*shsI8_t[tt];
      float f1 = F[u3+1][eL]*shsI8_t[tt];
      float f2 = F[u3+2][eL]*shsI8_t[tt];
      _Pragma("unroll")
      for(int r=0;r<4;r++){
        VV[tt][r][0] = fmaf(f0, acc4[tt][r], VV[tt][r][0]);
        VV[tt][r][1] = fmaf(f1, acc4[tt][r], VV[tt][r][1]);
        VV[tt][r][2] = fmaf(f2, acc4[tt][r], VV[tt][r][2]);
      }
    }
  );
  LDS_PIPE(A2rV, biasV, 48, 56,                // path E
    int u3 = 16 + (ntile-48)*3;
    _Pragma("unroll")
    for(int tt=0; tt<4; ++tt){
      int eL = tt*16+e16;
      float a0 = F[u3+0][eL], a1 = F[u3+1][eL], a2 = F[u3+2][eL];
      float x0 = (a1*sv_t[tt][2] - a2*sv_t[tt][1])*INV_S8;
      float x1 = (a2*sv_t[tt][0] - a0*sv_t[tt][2])*INV_S8;
      float x2 = (a0*sv_t[tt][1] - a1*sv_t[tt][0])*INV_S8;
      _Pragma("unroll")
      for(int r=0;r<4;r++){
        VV[tt][r][0] = fmaf(x0, acc4[tt][r], VV[tt][r][0]);
        VV[tt][r][1] = fmaf(x1, acc4[tt][r], VV[tt][r][1]);
        VV[tt][r][2] = fmaf(x2, acc4[tt][r], VV[tt][r][2]);
      }
    }
  );
  #pragma unroll
  for(int tt=0; tt<4; ++tt){
    int eo = ebase + tt*16 + e16;
    float* op = EdgeV + (size_t)eo*64 + 16 + g*12;
    float v[12] = {VV[tt][0][0],VV[tt][0][1],VV[tt][0][2],
                   VV[tt][1][0],VV[tt][1][1],VV[tt][1][2],
                   VV[tt][2][0],VV[tt][2][1],VV[tt][2][2],
                   VV[tt][3][0],VV[tt][3][1],VV[tt][3][2]};
    #pragma unroll
    for(int k=0;k<6;k++)
      *(float2*)(op + k*2) = make_float2(v[k*2], v[k*2+1]);
  }
}

// ---------------- Edge K body: LDS-staged weights ---------------------------
__device__ __forceinline__ void edge_k_body(
    int blk, float (*F)[64],
    unsigned short (*wbuf)[2048], float (*bbuf)[64],
    const int* __restrict__ ei, const float* __restrict__ esh,
    const float* __restrict__ ef,
    const float* __restrict__ Gs, const float* __restrict__ Gv,
    const float* __restrict__ Qs, const float* __restrict__ Qv,
    const float* __restrict__ Wk1, const float* __restrict__ bk1,
    const unsigned short* __restrict__ A2rK, const float* __restrict__ biasK,
    float* __restrict__ Attn){
  int wave = threadIdx.x >> 6, lane = threadIdx.x & 63;
  int ebase = blk*256 + wave*64;
  int e = ebase + lane;
  int e16 = lane & 15, g = lane >> 4;

  int dst = ei[e];
  float4 sh4 = *(const float4*)(esh + (size_t)e*4);
  float shs = sh4.x, sv0 = sh4.y, sv1 = sh4.z, sv2 = sh4.w;

  s16x8 af[4];
  HID_TO_FRAGS(Wk1, bk1);
  float shs_t[4], sv_t[4][3], shsI8_t[4];
  STAGE_FEATURES();

  // ---- paths A+B: ntiles 0..23 -> KS ----
  float KS[4][4] = {};
  LDS_PIPE(A2rK, biasK, 0, 16,
    _Pragma("unroll")
    for(int tt=0; tt<4; ++tt){
      float f = F[ntile][tt*16+e16] * shs_t[tt];
      _Pragma("unroll")
      for(int r=0;r<4;r++) KS[tt][r] = fmaf(f, acc4[tt][r], KS[tt][r]);
    }
  );
  LDS_PIPE(A2rK, biasK, 16, 24,
    int u3 = 16 + (ntile-16)*3;
    _Pragma("unroll")
    for(int tt=0; tt<4; ++tt){
      int eL = tt*16+e16;
      float f = (F[u3+0][eL]*sv_t[tt][0] + F[u3+1][eL]*sv_t[tt][1]
               + F[u3+2][eL]*sv_t[tt][2]) * INV_S8;
      _Pragma("unroll")
      for(int r=0;r<4;r++) KS[tt][r] = fmaf(f, acc4[tt][r], KS[tt][r]);
    }
  );
  // fold KS -> per-lane scalar dot (head h = g); KS dies
  int src_t[4]; float ksd[4];
  #pragma unroll
  for(int tt=0; tt<4; ++tt){
    int eo = ebase + tt*16 + e16;
    src_t[tt] = ei[EE + eo];
    float4 q4 = *(const float4*)(Qs + (size_t)src_t[tt]*16 + g*4);
    ksd[tt] = q4.x*KS[tt][0] + q4.y*KS[tt][1] + q4.z*KS[tt][2] + q4.w*KS[tt][3];
  }

  // ---- paths C+D+E: ntiles 24..39 -> KV (w = (g&1)*4+r, u-halves by g>>1) --
  float KV[4][4][3] = {};
  int gh = g >> 1;
  LDS_PIPE(A2rK, biasK, 24, 32,                // path C
    int fr = (ntile-24)*2 + gh;
    _Pragma("unroll")
    for(int tt=0; tt<4; ++tt){
      float f = F[fr][tt*16+e16];
      _Pragma("unroll")
      for(int r=0;r<4;r++){
        float c = f*acc4[tt][r];
        KV[tt][r][0] = fmaf(c, sv_t[tt][0], KV[tt][r][0]);
        KV[tt][r][1] = fmaf(c, sv_t[tt][1], KV[tt][r][1]);
        KV[tt][r][2] = fmaf(c, sv_t[tt][2], KV[tt][r][2]);
      }
    }
  );
  LDS_PIPE(A2rK, biasK, 32, 40,                // paths D (32..35) + E (36..39)
    if(ntile < 36){
      int u3 = 16 + ((ntile-32)*2 + gh)*3;
      _Pragma("unroll")
      for(int tt=0; tt<4; ++tt){
        int eL = tt*16+e16;
        float f0 = F[u3+0][eL]*shsI8_t[tt];
        float f1 = F[u3+1][eL]*shsI8_t[tt];
        float f2 = F[u3+2][eL]*shsI8_t[tt];
        _Pragma("unroll")
        for(int r=0;r<4;r++){
          KV[tt][r][0] = fmaf(f0, acc4[tt][r], KV[tt][r][0]);
          KV[tt][r][1] = fmaf(f1, acc4[tt][r], KV[tt][r][1]);
          KV[tt][r][2] = fmaf(f2, acc4[tt][r], KV[tt][r][2]);
        }
      }
    } else {
      int u3 = 16 + ((ntile-36)*2 + gh)*3;
      _Pragma("unroll")
      for(int tt=0; tt<4; ++tt){
        int eL = tt*16+e16;
        float a0 = F[u3+0][eL], a1 = F[u3+1][eL], a2 = F[u3+2][eL];
        float x0 = (a1*sv_t[tt][2] - a2*sv_t[tt][1])*INV_S8;
        float x1 = (a2*sv_t[tt][0] - a0*sv_t[tt][2])*INV_S8;
        float x2 = (a0*sv_t[tt][1] - a1*sv_t[tt][0])*INV_S8;
        _Pragma("unroll")
        for(int r=0;r<4;r++){
          KV[tt][r][0] = fmaf(x0, acc4[tt][r], KV[tt][r][0]);
          KV[tt][r][1] = fmaf(x1, acc4[tt][r], KV[tt][r][1]);
          KV[tt][r][2] = fmaf(x2, acc4[tt][r], KV[tt][r][2]);
        }
      }
    }
  );
  // ---- final: qv dot + cross-group reduce + write logits ----
  int godd = g & 1;
  #pragma unroll
  for(int tt=0; tt<4; ++tt){
    const float* qvp = Qv + (size_t)src_t[tt]*24 + godd*12;
    float4 qa = *(const float4*)(qvp);
    float4 qb = *(const float4*)(qvp+4);
    float4 qc = *(const float4*)(qvp+8);
    float kvs0 = qa.x*KV[tt][0][0] + qa.y*KV[tt][0][1] + qa.z*KV[tt][0][2]
               + qa.w*KV[tt][1][0] + qb.x*KV[tt][1][1] + qb.y*KV[tt][1][2];
    float kvs1 = qb.z*KV[tt][2][0] + qb.w*KV[tt][2][1] + qc.x*KV[tt][2][2]
               + qc.y*KV[tt][3][0] + qc.z*KV[tt][3][1] + qc.w*KV[tt][3][2];
    float p0 = ((g==0)? ksd[tt] : 0.f) + (godd? 0.f : kvs0);
    float p1 = ((g==1)? ksd[tt] : 0.f) + (godd? 0.f : kvs1);
    float p2 = ((g==2)? ksd[tt] : 0.f) + (godd? kvs0 : 0.f);
    float p3 = ((g==3)? ksd[tt] : 0.f) + (godd? kvs1 : 0.f);
    p0 += __shfl_xor(p0,16); p0 += __shfl_xor(p0,32);
    p1 += __shfl_xor(p1,16); p1 += __shfl_xor(p1,32);
    p2 += __shfl_xor(p2,16); p2 += __shfl_xor(p2,32);
    p3 += __shfl_xor(p3,16); p3 += __shfl_xor(p3,32);
    if(lane < 16){
      int eo = ebase + tt*16 + lane;
      *(float4*)(Attn + (size_t)eo*4) = make_float4(p0, p1, p2, p3);
    }
  }
}

// ---------------- Merged edge kernel: V-blocks then K-blocks ---------------
__global__ __launch_bounds__(256) void k_edge_vk(
    const int* __restrict__ ei, const float* __restrict__ esh,
    const float* __restrict__ ef,
    const float* __restrict__ Gs, const float* __restrict__ Gv,
    const float* __restrict__ Qs, const float* __restrict__ Qv,
    const float* __restrict__ Wv1, const float* __restrict__ bv1,
    const float* __restrict__ Wk1, const float* __restrict__ bk1,
    const unsigned short* __restrict__ A2rV, const float* __restrict__ biasV,
    const unsigned short* __restrict__ A2rK, const float* __restrict__ biasK,
    float* __restrict__ EdgeV, float* __restrict__ Attn){
  __shared__ float featAll[4][40][64];          // 40 KB
  __shared__ unsigned short wbuf[2][2048];      // 8 KB
  __shared__ float bbuf[2][64];                 // 512 B
  float (*F)[64] = featAll[threadIdx.x >> 6];
  if(blockIdx.x < NVB)
    edge_v_body(blockIdx.x, F, wbuf, bbuf, ei, esh, ef, Gs, Gv, Wv1, bv1, A2rV, biasV, EdgeV);
  else
    edge_k_body(blockIdx.x - NVB, F, wbuf, bbuf, ei, esh, ef, Gs, Gv, Qs, Qv, Wk1, bk1, A2rK, biasK, Attn);
}

// ---------------- per-node softmax + weighted sum (no atomics) -------------
__global__ __launch_bounds__(256) void k_reduce(
    const int* __restrict__ ofs, const int* __restrict__ elist,
    const float* __restrict__ Attn, const float* __restrict__ EdgeV,
    float* __restrict__ Upd){
  int wid = threadIdx.x >> 6, ln = threadIdx.x & 63;
  int n = blockIdx.x*4 + wid;
  if(n >= NN) return;
  int beg = ofs[n], end = ofs[n+1];
  float m0=-3.4e38f, m1=-3.4e38f, m2=-3.4e38f, m3=-3.4e38f;
  for(int i=beg+ln; i<end; i+=64){
    int e = elist[i];
    float4 a = *(const float4*)(Attn + (size_t)e*4);
    m0=fmaxf(m0,a.x); m1=fmaxf(m1,a.y); m2=fmaxf(m2,a.z); m3=fmaxf(m3,a.w);
  }
  #pragma unroll
  for(int off=1; off<64; off<<=1){
    m0=fmaxf(m0,__shfl_xor(m0,off)); m1=fmaxf(m1,__shfl_xor(m1,off));
    m2=fmaxf(m2,__shfl_xor(m2,off)); m3=fmaxf(m3,__shfl_xor(m3,off));
  }
  int h = (ln < 16) ? (ln >> 2) : (((ln - 16)/3) >> 2);
  float mh = (h==0)?m0:(h==1)?m1:(h==2)?m2:m3;
  float acc = 0.f, den = 0.f;
  for(int i=beg; i<end; i++){
    int e = elist[i];
    float v  = EdgeV[(size_t)e*64 + ln];
    float a  = Attn[(size_t)e*4 + h];
    float ex = __expf(a - mh);
    acc = fmaf(ex, v, acc);
    den += ex;
  }
  Upd[(size_t)n*64 + ln] = acc / (den + 1e-9f);
}

// ---------------- node output GEMMs: thread-per-(node,channel) -------------
__global__ __launch_bounds__(256) void k_nodeout(
    const float* __restrict__ Upd, const float* __restrict__ tfn,
    const float* __restrict__ Wos, const float* __restrict__ Wov,
    const float* __restrict__ Wss, const float* __restrict__ Wsv,
    float* __restrict__ Pre){
  int idx = blockIdx.x*256 + threadIdx.x;
  if(idx >= NN*40) return;
  int n = idx/40, c = idx - n*40;
  const float* up = Upd + (size_t)n*64;
  const float* tp = tfn + (size_t)n*40;
  float out;
  if(c < 16){
    float a=0.f, b=0.f;
    #pragma unroll
    for(int u=0;u<16;u++){
      a = fmaf(up[u], Wos[u*16+c], a);
      b = fmaf(tp[u], Wss[u*16+c], b);
    }
    out = (a+b)*0.25f;
  } else {
    int w = (c-16)/3, i = (c-16)%3;
    float a=0.f, b=0.f;
    #pragma unroll
    for(int u=0;u<16;u++) a = fmaf(up[16+u*3+i], Wov[u*8+w], a);
    #pragma unroll
    for(int u=0;u<8;u++)  b = fmaf(tp[16+u*3+i], Wsv[u*8+w], b);
    out = a*0.25f + b*INV_S8;
  }
  Pre[idx] = out;
}

// ---------------- BN stats: 24 blocks, column-streaming, no atomics --------
__global__ __launch_bounds__(256) void k_stats(
    const float* __restrict__ Pre, float* __restrict__ Stats){
  int b = blockIdx.x;
  int lane = threadIdx.x & 63, wave = threadIdx.x >> 6;
  float s1 = 0.f, s2 = 0.f;
  if(b < 16){
    for(int n = threadIdx.x; n < NN; n += 256){
      float x = Pre[(size_t)n*40 + b];
      s1 += x; s2 += x*x;
    }
  } else {
    int w3 = 16 + (b-16)*3;
    for(int n = threadIdx.x; n < NN; n += 256){
      const float* p = Pre + (size_t)n*40 + w3;
      s1 += p[0]*p[0] + p[1]*p[1] + p[2]*p[2];
    }
  }
  #pragma unroll
  for(int off=1; off<64; off<<=1){
    s1 += __shfl_xor(s1, off);
    s2 += __shfl_xor(s2, off);
  }
  __shared__ float ws1[4], ws2[4];
  if(lane == 0){ ws1[wave] = s1; ws2[wave] = s2; }
  __syncthreads();
  if(threadIdx.x == 0){
    float t1 = ws1[0]+ws1[1]+ws1[2]+ws1[3];
    float t2 = ws2[0]+ws2[1]+ws2[2]+ws2[3];
    if(b < 16){ Stats[b] = t1; Stats[16+b] = t2; }
    else        Stats[32+(b-16)] = t1;
  }
}

// ---------------- finalize BN + write output -------------------------------
__global__ __launch_bounds__(256) void k_final(
    const float* __restrict__ Pre, const float* __restrict__ Stats,
    const float* __restrict__ bnws, const float* __restrict__ bnbs,
    const float* __restrict__ bnwv, float* __restrict__ Out){
  int idx = blockIdx.x*256 + threadIdx.x;
  if(idx >= NN*40) return;
  int n = idx/40, c = idx - n*40;
  float x = Pre[idx];
  float r;
  if(c < 16){
    float mu  = Stats[c]    * (1.f/NN);
    float var = Stats[16+c] * (1.f/NN) - mu*mu;
    r = (x - mu) / sqrtf(var + 1e-5f) * bnws[c] + bnbs[c];
  } else {
    int w = (c-16)/3;
    float n2 = Stats[32+w] * (1.f/NN);
    r = x / sqrtf(n2 + 1e-5f) * bnwv[w];
  }
  Out[idx] = r;
}

extern "C" void kernel_launch(void* const* d_in, const int* in_sizes, int n_in,
                              void* d_out, int out_size, void* d_ws, size_t ws_size,
                              hipStream_t stream){
  const float* frame = (const float*)d_in[0];
  const float* rot   = (const float*)d_in[1];
  const float* trans = (const float*)d_in[2];
  const float* tfn   = (const float*)d_in[3];
  const float* ef    = (const float*)d_in[4];
  const float* esh   = (const float*)d_in[5];
  const int*   ei    = (const int*)  d_in[6];
  const float* Wf0   = (const float*)d_in[7];
  const float* bf0   = (const float*)d_in[8];
  const float* Wf1   = (const float*)d_in[9];
  const float* bf1   = (const float*)d_in[10];
  const float* Wgs   = (const float*)d_in[11];
  const float* Wgv   = (const float*)d_in[12];
  const float* Wqs   = (const float*)d_in[13];
  const float* Wqv   = (const float*)d_in[14];
  const float* Wk1   = (const float*)d_in[15];
  const float* bk1   = (const float*)d_in[16];
  const float* Wk2   = (const float*)d_in[17];
  const float* bk2   = (const float*)d_in[18];
  const float* Wv1   = (const float*)d_in[19];
  const float* bv1   = (const float*)d_in[20];
  const float* Wv2   = (const float*)d_in[21];
  const float* bv2   = (const float*)d_in[22];
  const float* Wos   = (const float*)d_in[23];
  const float* Wov   = (const float*)d_in[24];
  const float* Wss   = (const float*)d_in[25];
  const float* Wsv   = (const float*)d_in[26];
  const float* bnws  = (const float*)d_in[27];
  const float* bnbs  = (const float*)d_in[28];
  const float* bnwv  = (const float*)d_in[29];

  float* ws   = (float*)d_ws;
  float* f0f1 = ws;                                   // N*160 (unused now)
  float* Gs   = f0f1 + (size_t)NN*160;                // N*16
  float* Gv   = Gs   + (size_t)NN*16;                 // N*24
  float* Qs   = Gv   + (size_t)NN*24;                 // N*16
  float* Qv   = Qs   + (size_t)NN*16;                 // N*24
  float* Attn = Qv   + (size_t)NN*24;                 // E*4
  float* Pre  = Attn + (size_t)EE*4;                  // N*40
  float* Upd  = Pre  + (size_t)NN*40;                 // N*64
  float* EdgeV= Upd  + (size_t)NN*64;                 // E*64
  float* Stats= EdgeV+ (size_t)EE*64;                 // 64 floats
  int*   cnt  = (int*)(Stats + 64);                   // N+16   (zeroed)
  int*   ofs  = cnt + (NN+16);                        // N+16 (use [0..N])
  int*   fill = ofs + (NN+16);                        // N+16
  int*   elist= fill + (NN+16);                       // E
  float* biasV= (float*)(elist + EE);                 // 896  (16B-aligned)
  float* biasK= biasV + 896;                          // 640
  unsigned short* A2rV = (unsigned short*)(biasK + 640);  // 896*32
  unsigned short* A2rK = A2rV + 896*32;                   // 640*32

  hipMemsetAsync(cnt, 0, (NN + 16)*sizeof(int), stream);

  k_node    <<<dim3(NN),              192, 0, stream>>>(frame, Wf0, bf0, Wf1, bf1,
                                                        rot, trans, tfn,
                                                        Wgs, Wgv, Wqs, Wqv,
                                                        Gs, Gv, Qs, Qv);
  k_prepw   <<<dim3(198),             256, 0, stream>>>(Wk2, bk2, Wv2, bv2, A2rK, A2rV, biasK, biasV);
  k_hist    <<<dim3((EE+255)/256),    256, 0, stream>>>(ei, cnt);
  k_scan    <<<dim3(1),               256, 0, stream>>>(cnt, ofs, fill);
  k_scatter <<<dim3((EE+255)/256),    256, 0, stream>>>(ei, fill, elist);
  k_edge_vk <<<dim3(2*NVB),           256, 0, stream>>>(ei, esh, ef, Gs, Gv, Qs, Qv,
                                                        Wv1, bv1, Wk1, bk1,
                                                        A2rV, biasV, A2rK, biasK,
                                                        EdgeV, Attn);
  k_reduce  <<<dim3((NN+3)/4),        256, 0, stream>>>(ofs, elist, Attn, EdgeV, Upd);
  k_nodeout <<<dim3((NN*40+255)/256), 256, 0, stream>>>(Upd, tfn, Wos, Wov, Wss, Wsv, Pre);
  k_stats   <<<dim3(24),              256, 0, stream>>>(Pre, Stats);
  k_final   <<<dim3((NN*40+255)/256), 256, 0, stream>>>(Pre, Stats, bnws, bnbs, bnwv, (float*)d_out);
}

// Round 17
// 257.604 us; speedup vs baseline: 1.0419x; 1.0419x over previous
//
#include <hip/hip_runtime.h>
#include <hip/hip_bf16.h>
#include <math.h>

#define NN 10000
#define EE 160000
#define CSZ 128
#define NVB (EE/128)   // 1250 V-blocks, then 1250 K-blocks

#define INV_S8  0.35355339059327373f   // 1/sqrt(8)
#define INV_S32 0.17677669529663687f   // 1/sqrt(32)
#define INV_S2  0.7071067811865476f    // 1/sqrt(2)
#define INV_S3  0.5773502691896258f    // 1/sqrt(3)

typedef short s16x8 __attribute__((ext_vector_type(8)));
typedef float f32x4 __attribute__((ext_vector_type(4)));

__device__ __forceinline__ unsigned short f2bf(float f){
  __hip_bfloat16 h = __float2bfloat16(f);
  return *reinterpret_cast<unsigned short*>(&h);
}

// ---------------- Fused node kernel: f0/f1 GEMM + rotate + gs/gv/qs/qv -----
__global__ __launch_bounds__(192) void k_node(
    const float* __restrict__ frame,
    const float* __restrict__ Wf0, const float* __restrict__ bf0,
    const float* __restrict__ Wf1, const float* __restrict__ bf1,
    const float* __restrict__ rot, const float* __restrict__ trans,
    const float* __restrict__ tfn,
    const float* __restrict__ Wgs, const float* __restrict__ Wgv,
    const float* __restrict__ Wqs, const float* __restrict__ Wqv,
    float* __restrict__ Gs, float* __restrict__ Gv,
    float* __restrict__ Qs, float* __restrict__ Qv){
  __shared__ float ff[160];
  __shared__ float f1r[32][3];
  int n = blockIdx.x;
  int t = threadIdx.x;
  if(t < 160){
    bool is0 = t < 64;
    int cc = is0 ? t : (t-64);
    const float* W = is0 ? Wf0 : Wf1;
    int ldw = is0 ? 64 : 96;
    float acc = is0 ? bf0[cc] : bf1[cc];
    const float* fp = frame + (size_t)n*CSZ;
    #pragma unroll 8
    for(int k=0;k<CSZ;k++)
      acc = fmaf(fp[k], W[k*ldw + cc], acc);
    ff[t] = acc;
  }
  __syncthreads();
  if(t < 32){
    float v0 = ff[64+t*3+0], v1 = ff[64+t*3+1], v2 = ff[64+t*3+2];
    const float* R = rot + (size_t)n*9;
    const float* tr = trans + (size_t)n*3;
    f1r[t][0] = R[0]*v0 + R[1]*v1 + R[2]*v2 + tr[0];
    f1r[t][1] = R[3]*v0 + R[4]*v1 + R[5]*v2 + tr[1];
    f1r[t][2] = R[6]*v0 + R[7]*v1 + R[8]*v2 + tr[2];
  }
  __syncthreads();
  if(t < 16){
    float a = 0.f;
    #pragma unroll
    for(int u=0;u<64;u++) a = fmaf(ff[u], Wgs[u*16+t], a);
    Gs[(size_t)n*16+t] = a * 0.125f;
  } else if(t < 40){
    int idx = t-16, w = idx/3, i = idx%3; float a = 0.f;
    #pragma unroll
    for(int u=0;u<32;u++) a = fmaf(f1r[u][i], Wgv[u*8+w], a);
    Gv[(size_t)n*24+idx] = a * INV_S32;
  } else if(t < 56){
    int w = t-40; float a = 0.f;
    #pragma unroll
    for(int u=0;u<16;u++) a = fmaf(tfn[(size_t)n*40+u], Wqs[u*16+w], a);
    Qs[(size_t)n*16+w] = a * 0.25f;
  } else if(t < 80){
    int idx = t-56, w = idx/3, i = idx%3; float a = 0.f;
    #pragma unroll
    for(int u=0;u<8;u++) a = fmaf(tfn[(size_t)n*40+16+u*3+i], Wqv[u*8+w], a);
    Qv[(size_t)n*24+idx] = a * INV_S8;
  }
}

// ---------------- CSR build ------------------------------------------------
__global__ __launch_bounds__(256) void k_hist(const int* __restrict__ ei, int* __restrict__ cnt){
  int e = blockIdx.x*256 + threadIdx.x;
  if(e < EE) atomicAdd(&cnt[ei[EE + e]], 1);
}

__global__ __launch_bounds__(256) void k_scan(const int* __restrict__ cnt,
                                              int* __restrict__ ofs, int* __restrict__ fill){
  __shared__ int tsum[256];
  int t = threadIdx.x;
  const int CH = (NN + 255)/256;
  int base = t*CH;
  int s = 0;
  for(int i=0;i<CH;i++){ int idx=base+i; if(idx<NN) s += cnt[idx]; }
  tsum[t] = s;
  __syncthreads();
  for(int off=1; off<256; off<<=1){
    int v = (t>=off)? tsum[t-off] : 0;
    __syncthreads();
    tsum[t] += v;
    __syncthreads();
  }
  int run = (t==0)? 0 : tsum[t-1];
  for(int i=0;i<CH;i++){
    int idx = base+i;
    if(idx < NN){ ofs[idx] = run; fill[idx] = run; run += cnt[idx]; }
  }
  if(t==255) ofs[NN] = tsum[255];
}

__global__ __launch_bounds__(256) void k_scatter(const int* __restrict__ ei,
                                                 int* __restrict__ fill, int* __restrict__ elist){
  int e = blockIdx.x*256 + threadIdx.x;
  if(e >= EE) return;
  int src = ei[EE + e];
  int pos = atomicAdd(&fill[src], 1);
  elist[pos] = e;
}

// ---------------- Weight reshape: W2 -> MFMA A-fragment order, bf16 --------
__global__ __launch_bounds__(256) void k_prepw(
    const float* __restrict__ Wk2, const float* __restrict__ bk2,
    const float* __restrict__ Wv2, const float* __restrict__ bv2,
    unsigned short* __restrict__ A2rK, unsigned short* __restrict__ A2rV,
    float* __restrict__ biasK, float* __restrict__ biasV){
  int tid = blockIdx.x*256 + threadIdx.x;
  const int NV = 896*32, NK = 640*32;
  if(tid < NV){
    int c = tid>>5, h = tid&31;
    float s = (c<384)? INV_S2 : INV_S3;
    A2rV[(c>>4)*512 + (c&15)*32 + h] = f2bf(Wv2[h*896+c]*s);
  } else if(tid < NV+NK){
    int i = tid - NV; int c = i>>5, h = i&31;
    float s = (c<384)? INV_S2 : INV_S3;
    A2rK[(c>>4)*512 + (c&15)*32 + h] = f2bf(Wk2[h*640+c]*s);
  } else if(tid < NV+NK+896){
    int c = tid - (NV+NK);
    biasV[c] = bv2[c] * ((c<384)? INV_S2 : INV_S3);
  } else if(tid < NV+NK+896+640){
    int c = tid - (NV+NK+896);
    biasK[c] = bk2[c] * ((c<384)? INV_S2 : INV_S3);
  }
}

// hidden MLP -> LDS fragments -> af[4] regs (B-operand frags). hL overlays F.
#define HID_TO_FRAGS(W1, b1) { \
  unsigned short* hL = (unsigned short*)&F[0][0]; \
  float efv[32]; \
  const float4* efp = (const float4*)(ef + (size_t)e*32); \
  _Pragma("unroll") \
  for(int q=0;q<8;q++){ float4 t=efp[q]; efv[q*4]=t.x; efv[q*4+1]=t.y; efv[q*4+2]=t.z; efv[q*4+3]=t.w; } \
  float hd[32]; \
  _Pragma("unroll") \
  for(int h=0;h<32;h++) hd[h] = b1[h]; \
  _Pragma("unroll") \
  for(int k=0;k<32;k++){ \
    float ekv = efv[k]; \
    _Pragma("unroll") \
    for(int h=0;h<32;h++) hd[h] = fmaf(ekv, W1[k*32+h], hd[h]); \
  } \
  _Pragma("unroll") \
  for(int gg=0;gg<4;gg++){ \
    s16x8 p; \
    _Pragma("unroll") \
    for(int j=0;j<8;j++) p[j] = (short)f2bf(fmaxf(hd[gg*8+j], 0.f)); \
    *(s16x8*)&hL[((g*4+gg)*16 + e16)*8] = p; \
  } \
  _Pragma("unroll") \
  for(int tt=0;tt<4;tt++) \
    af[tt] = *(const s16x8*)&hL[((tt*4 + g)*16 + e16)*8]; }

// features -> LDS (rows 0..15 fsn=Gs*0.25, rows 16..39 fv) + sh via shfl
#define STAGE_FEATURES() { \
  const float4* g4 = (const float4*)(Gs + (size_t)dst*16); \
  _Pragma("unroll") \
  for(int q=0;q<4;q++){ float4 t = g4[q]; \
    F[q*4+0][lane]=t.x*0.25f; F[q*4+1][lane]=t.y*0.25f; \
    F[q*4+2][lane]=t.z*0.25f; F[q*4+3][lane]=t.w*0.25f; } \
  const float4* v4 = (const float4*)(Gv + (size_t)dst*24); \
  _Pragma("unroll") \
  for(int q=0;q<6;q++){ float4 t = v4[q]; \
    F[16+q*4+0][lane]=t.x; F[16+q*4+1][lane]=t.y; \
    F[16+q*4+2][lane]=t.z; F[16+q*4+3][lane]=t.w; } \
  _Pragma("unroll") \
  for(int tt=0;tt<4;tt++){ \
    int sl = tt*16 + e16; \
    shs_t[tt]  = __shfl(shs, sl); \
    sv_t[tt][0]= __shfl(sv0, sl); \
    sv_t[tt][1]= __shfl(sv1, sl); \
    sv_t[tt][2]= __shfl(sv2, sl); \
    shsI8_t[tt]= shs_t[tt]*INV_S8; \
  } }

// per-ntile MFMA: load weight frag + bias, 4 MFMAs into acc4[tt]
#define NTILE_MFMA(A2r, bias, NT) \
  s16x8 Aw = *(const s16x8*)&A2r[(NT)*512 + e16*32 + g*8]; \
  float4 b4 = *(const float4*)&bias[(NT)*16 + g*4]; \
  f32x4 acc4[4]; \
  _Pragma("unroll") \
  for(int tt=0; tt<4; ++tt){ \
    f32x4 a0 = {b4.x, b4.y, b4.z, b4.w}; \
    acc4[tt] = __builtin_amdgcn_mfma_f32_16x16x32_bf16(Aw, af[tt], a0, 0, 0, 0); \
  }

// ---------------- Edge V body: transposed MFMA, unroll-1 chunk loops -------
__device__ __forceinline__ void edge_v_body(
    int blk, float (*F)[64],
    const int* __restrict__ ei, const float* __restrict__ esh,
    const float* __restrict__ ef,
    const float* __restrict__ Gs, const float* __restrict__ Gv,
    const float* __restrict__ Wv1, const float* __restrict__ bv1,
    const unsigned short* __restrict__ A2rV, const float* __restrict__ biasV,
    float* __restrict__ EdgeV){
  int wave = threadIdx.x >> 6, lane = threadIdx.x & 63;
  int ebase = blk*128 + wave*64;
  int e = ebase + lane;
  int e16 = lane & 15, g = lane >> 4;

  int dst = ei[e];
  float4 sh4 = *(const float4*)(esh + (size_t)e*4);
  float shs = sh4.x, sv0 = sh4.y, sv1 = sh4.z, sv2 = sh4.w;

  s16x8 af[4];
  HID_TO_FRAGS(Wv1, bv1);
  float shs_t[4], sv_t[4][3], shsI8_t[4];
  STAGE_FEATURES();

  // ---- path A: ntiles 0..15 ----
  float A16[4][4] = {};
  #pragma unroll 1
  for(int ntile=0; ntile<16; ++ntile){
    NTILE_MFMA(A2rV, biasV, ntile);
    #pragma unroll
    for(int tt=0; tt<4; ++tt){
      float f = F[ntile][tt*16+e16] * shs_t[tt];
      #pragma unroll
      for(int r=0;r<4;r++) A16[tt][r] = fmaf(f, acc4[tt][r], A16[tt][r]);
    }
  }
  // ---- path B: ntiles 16..23 ----
  #pragma unroll 1
  for(int ntile=16; ntile<24; ++ntile){
    NTILE_MFMA(A2rV, biasV, ntile);
    int u3 = 16 + (ntile-16)*3;
    #pragma unroll
    for(int tt=0; tt<4; ++tt){
      int eL = tt*16+e16;
      float f = (F[u3+0][eL]*sv_t[tt][0] + F[u3+1][eL]*sv_t[tt][1]
               + F[u3+2][eL]*sv_t[tt][2]) * INV_S8;
      #pragma unroll
      for(int r=0;r<4;r++) A16[tt][r] = fmaf(f, acc4[tt][r], A16[tt][r]);
    }
  }
  #pragma unroll
  for(int tt=0; tt<4; ++tt){
    int eo = ebase + tt*16 + e16;
    *(float4*)(EdgeV + (size_t)eo*64 + g*4) =
        make_float4(A16[tt][0], A16[tt][1], A16[tt][2], A16[tt][3]);
  }

  // ---- paths C+D+E: ntiles 24..55 -> vector outputs VV ----
  float VV[4][4][3] = {};
  #pragma unroll 1
  for(int ntile=24; ntile<40; ++ntile){        // path C
    NTILE_MFMA(A2rV, biasV, ntile);
    #pragma unroll
    for(int tt=0; tt<4; ++tt){
      float f = F[ntile-24][tt*16+e16];
      #pragma unroll
      for(int r=0;r<4;r++){
        float c = f*acc4[tt][r];
        VV[tt][r][0] = fmaf(c, sv_t[tt][0], VV[tt][r][0]);
        VV[tt][r][1] = fmaf(c, sv_t[tt][1], VV[tt][r][1]);
        VV[tt][r][2] = fmaf(c, sv_t[tt][2], VV[tt][r][2]);
      }
    }
  }
  #pragma unroll 1
  for(int ntile=40; ntile<48; ++ntile){        // path D
    NTILE_MFMA(A2rV, biasV, ntile);
    int u3 = 16 + (ntile-40)*3;
    #pragma unroll
    for(int tt=0; tt<4; ++tt){
      int eL = tt*16+e16;
      float f0 = F[u3+0][eL]*shsI8_t[tt];
      float f1 = F[u3+1][eL]*shsI8_t[tt];
      float f2 = F[u3+2][eL]*shsI8_t[tt];
      #pragma unroll
      for(int r=0;r<4;r++){
        VV[tt][r][0] = fmaf(f0, acc4[tt][r], VV[tt][r][0]);
        VV[tt][r][1] = fmaf(f1, acc4[tt][r], VV[tt][r][1]);
        VV[tt][r][2] = fmaf(f2, acc4[tt][r], VV[tt][r][2]);
      }
    }
  }
  #pragma unroll 1
  for(int ntile=48; ntile<56; ++ntile){        // path E
    NTILE_MFMA(A2rV, biasV, ntile);
    int u3 = 16 + (ntile-48)*3;
    #pragma unroll
    for(int tt=0; tt<4; ++tt){
      int eL = tt*16+e16;
      float a0 = F[u3+0][eL], a1 = F[u3+1][eL], a2 = F[u3+2][eL];
      float x0 = (a1*sv_t[tt][2] - a2*sv_t[tt][1])*INV_S8;
      float x1 = (a2*sv_t[tt][0] - a0*sv_t[tt][2])*INV_S8;
      float x2 = (a0*sv_t[tt][1] - a1*sv_t[tt][0])*INV_S8;
      #pragma unroll
      for(int r=0;r<4;r++){
        VV[tt][r][0] = fmaf(x0, acc4[tt][r], VV[tt][r][0]);
        VV[tt][r][1] = fmaf(x1, acc4[tt][r], VV[tt][r][1]);
        VV[tt][r][2] = fmaf(x2, acc4[tt][r], VV[tt][r][2]);
      }
    }
  }
  #pragma unroll
  for(int tt=0; tt<4; ++tt){
    int eo = ebase + tt*16 + e16;
    float* op = EdgeV + (size_t)eo*64 + 16 + g*12;
    float v[12] = {VV[tt][0][0],VV[tt][0][1],VV[tt][0][2],
                   VV[tt][1][0],VV[tt][1][1],VV[tt][1][2],
                   VV[tt][2][0],VV[tt][2][1],VV[tt][2][2],
                   VV[tt][3][0],VV[tt][3][1],VV[tt][3][2]};
    #pragma unroll
    for(int k=0;k<6;k++)
      *(float2*)(op + k*2) = make_float2(v[k*2], v[k*2+1]);
  }
}

// ---------------- Edge K body: transposed MFMA, unroll-1 chunk loops -------
__device__ __forceinline__ void edge_k_body(
    int blk, float (*F)[64],
    const int* __restrict__ ei, const float* __restrict__ esh,
    const float* __restrict__ ef,
    const float* __restrict__ Gs, const float* __restrict__ Gv,
    const float* __restrict__ Qs, const float* __restrict__ Qv,
    const float* __restrict__ Wk1, const float* __restrict__ bk1,
    const unsigned short* __restrict__ A2rK, const float* __restrict__ biasK,
    float* __restrict__ Attn){
  int wave = threadIdx.x >> 6, lane = threadIdx.x & 63;
  int ebase = blk*128 + wave*64;
  int e = ebase + lane;
  int e16 = lane & 15, g = lane >> 4;

  int dst = ei[e];
  float4 sh4 = *(const float4*)(esh + (size_t)e*4);
  float shs = sh4.x, sv0 = sh4.y, sv1 = sh4.z, sv2 = sh4.w;

  s16x8 af[4];
  HID_TO_FRAGS(Wk1, bk1);
  float shs_t[4], sv_t[4][3], shsI8_t[4];
  STAGE_FEATURES();

  // ---- path A: ntiles 0..15 ----
  float KS[4][4] = {};
  #pragma unroll 1
  for(int ntile=0; ntile<16; ++ntile){
    NTILE_MFMA(A2rK, biasK, ntile);
    #pragma unroll
    for(int tt=0; tt<4; ++tt){
      float f = F[ntile][tt*16+e16] * shs_t[tt];
      #pragma unroll
      for(int r=0;r<4;r++) KS[tt][r] = fmaf(f, acc4[tt][r], KS[tt][r]);
    }
  }
  // ---- path B: ntiles 16..23 ----
  #pragma unroll 1
  for(int ntile=16; ntile<24; ++ntile){
    NTILE_MFMA(A2rK, biasK, ntile);
    int u3 = 16 + (ntile-16)*3;
    #pragma unroll
    for(int tt=0; tt<4; ++tt){
      int eL = tt*16+e16;
      float f = (F[u3+0][eL]*sv_t[tt][0] + F[u3+1][eL]*sv_t[tt][1]
               + F[u3+2][eL]*sv_t[tt][2]) * INV_S8;
      #pragma unroll
      for(int r=0;r<4;r++) KS[tt][r] = fmaf(f, acc4[tt][r], KS[tt][r]);
    }
  }
  // fold KS -> per-lane scalar dot (head h = g); KS dies
  int src_t[4]; float ksd[4];
  #pragma unroll
  for(int tt=0; tt<4; ++tt){
    int eo = ebase + tt*16 + e16;
    src_t[tt] = ei[EE + eo];
    float4 q4 = *(const float4*)(Qs + (size_t)src_t[tt]*16 + g*4);
    ksd[tt] = q4.x*KS[tt][0] + q4.y*KS[tt][1] + q4.z*KS[tt][2] + q4.w*KS[tt][3];
  }

  // ---- paths C+D+E: ntiles 24..39 -> KV (w = (g&1)*4+r, u-halves by g>>1) --
  float KV[4][4][3] = {};
  int gh = g >> 1;
  #pragma unroll 1
  for(int ntile=24; ntile<32; ++ntile){        // path C
    NTILE_MFMA(A2rK, biasK, ntile);
    int fr = (ntile-24)*2 + gh;
    #pragma unroll
    for(int tt=0; tt<4; ++tt){
      float f = F[fr][tt*16+e16];
      #pragma unroll
      for(int r=0;r<4;r++){
        float c = f*acc4[tt][r];
        KV[tt][r][0] = fmaf(c, sv_t[tt][0], KV[tt][r][0]);
        KV[tt][r][1] = fmaf(c, sv_t[tt][1], KV[tt][r][1]);
        KV[tt][r][2] = fmaf(c, sv_t[tt][2], KV[tt][r][2]);
      }
    }
  }
  #pragma unroll 1
  for(int ntile=32; ntile<36; ++ntile){        // path D
    NTILE_MFMA(A2rK, biasK, ntile);
    int u3 = 16 + ((ntile-32)*2 + gh)*3;
    #pragma unroll
    for(int tt=0; tt<4; ++tt){
      int eL = tt*16+e16;
      float f0 = F[u3+0][eL]*shsI8_t[tt];
      float f1 = F[u3+1][eL]*shsI8_t[tt];
      float f2 = F[u3+2][eL]*shsI8_t[tt];
      #pragma unroll
      for(int r=0;r<4;r++){
        KV[tt][r][0] = fmaf(f0, acc4[tt][r], KV[tt][r][0]);
        KV[tt][r][1] = fmaf(f1, acc4[tt][r], KV[tt][r][1]);
        KV[tt][r][2] = fmaf(f2, acc4[tt][r], KV[tt][r][2]);
      }
    }
  }
  #pragma unroll 1
  for(int ntile=36; ntile<40; ++ntile){        // path E
    NTILE_MFMA(A2rK, biasK, ntile);
    int u3 = 16 + ((ntile-36)*2 + gh)*3;
    #pragma unroll
    for(int tt=0; tt<4; ++tt){
      int eL = tt*16+e16;
      float a0 = F[u3+0][eL], a1 = F[u3+1][eL], a2 = F[u3+2][eL];
      float x0 = (a1*sv_t[tt][2] - a2*sv_t[tt][1])*INV_S8;
      float x1 = (a2*sv_t[tt][0] - a0*sv_t[tt][2])*INV_S8;
      float x2 = (a0*sv_t[tt][1] - a1*sv_t[tt][0])*INV_S8;
      #pragma unroll
      for(int r=0;r<4;r++){
        KV[tt][r][0] = fmaf(x0, acc4[tt][r], KV[tt][r][0]);
        KV[tt][r][1] = fmaf(x1, acc4[tt][r], KV[tt][r][1]);
        KV[tt][r][2] = fmaf(x2, acc4[tt][r], KV[tt][r][2]);
      }
    }
  }
  // ---- final: qv dot + cross-group reduce + write logits ----
  int godd = g & 1;
  #pragma unroll
  for(int tt=0; tt<4; ++tt){
    const float* qvp = Qv + (size_t)src_t[tt]*24 + godd*12;
    float4 qa = *(const float4*)(qvp);
    float4 qb = *(const float4*)(qvp+4);
    float4 qc = *(const float4*)(qvp+8);
    float kvs0 = qa.x*KV[tt][0][0] + qa.y*KV[tt][0][1] + qa.z*KV[tt][0][2]
               + qa.w*KV[tt][1][0] + qb.x*KV[tt][1][1] + qb.y*KV[tt][1][2];
    float kvs1 = qb.z*KV[tt][2][0] + qb.w*KV[tt][2][1] + qc.x*KV[tt][2][2]
               + qc.y*KV[tt][3][0] + qc.z*KV[tt][3][1] + qc.w*KV[tt][3][2];
    float p0 = ((g==0)? ksd[tt] : 0.f) + (godd? 0.f : kvs0);
    float p1 = ((g==1)? ksd[tt] : 0.f) + (godd? 0.f : kvs1);
    float p2 = ((g==2)? ksd[tt] : 0.f) + (godd? kvs0 : 0.f);
    float p3 = ((g==3)? ksd[tt] : 0.f) + (godd? kvs1 : 0.f);
    p0 += __shfl_xor(p0,16); p0 += __shfl_xor(p0,32);
    p1 += __shfl_xor(p1,16); p1 += __shfl_xor(p1,32);
    p2 += __shfl_xor(p2,16); p2 += __shfl_xor(p2,32);
    p3 += __shfl_xor(p3,16); p3 += __shfl_xor(p3,32);
    if(lane < 16){
      int eo = ebase + tt*16 + lane;
      *(float4*)(Attn + (size_t)eo*4) = make_float4(p0, p1, p2, p3);
    }
  }
}

// ---------------- Merged edge kernel: V-blocks then K-blocks, one launch ---
__global__ __launch_bounds__(128) void k_edge_vk(
    const int* __restrict__ ei, const float* __restrict__ esh,
    const float* __restrict__ ef,
    const float* __restrict__ Gs, const float* __restrict__ Gv,
    const float* __restrict__ Qs, const float* __restrict__ Qv,
    const float* __restrict__ Wv1, const float* __restrict__ bv1,
    const float* __restrict__ Wk1, const float* __restrict__ bk1,
    const unsigned short* __restrict__ A2rV, const float* __restrict__ biasV,
    const unsigned short* __restrict__ A2rK, const float* __restrict__ biasK,
    float* __restrict__ EdgeV, float* __restrict__ Attn){
  __shared__ float featAll[2][40][64];
  float (*F)[64] = featAll[threadIdx.x >> 6];
  if(blockIdx.x < NVB)
    edge_v_body(blockIdx.x, F, ei, esh, ef, Gs, Gv, Wv1, bv1, A2rV, biasV, EdgeV);
  else
    edge_k_body(blockIdx.x - NVB, F, ei, esh, ef, Gs, Gv, Qs, Qv, Wk1, bk1, A2rK, biasK, Attn);
}

// ---------------- per-node softmax + weighted sum (no atomics) -------------
__global__ __launch_bounds__(256) void k_reduce(
    const int* __restrict__ ofs, const int* __restrict__ elist,
    const float* __restrict__ Attn, const float* __restrict__ EdgeV,
    float* __restrict__ Upd){
  int wid = threadIdx.x >> 6, ln = threadIdx.x & 63;
  int n = blockIdx.x*4 + wid;
  if(n >= NN) return;
  int beg = ofs[n], end = ofs[n+1];
  float m0=-3.4e38f, m1=-3.4e38f, m2=-3.4e38f, m3=-3.4e38f;
  for(int i=beg+ln; i<end; i+=64){
    int e = elist[i];
    float4 a = *(const float4*)(Attn + (size_t)e*4);
    m0=fmaxf(m0,a.x); m1=fmaxf(m1,a.y); m2=fmaxf(m2,a.z); m3=fmaxf(m3,a.w);
  }
  #pragma unroll
  for(int off=1; off<64; off<<=1){
    m0=fmaxf(m0,__shfl_xor(m0,off)); m1=fmaxf(m1,__shfl_xor(m1,off));
    m2=fmaxf(m2,__shfl_xor(m2,off)); m3=fmaxf(m3,__shfl_xor(m3,off));
  }
  int h = (ln < 16) ? (ln >> 2) : (((ln - 16)/3) >> 2);
  float mh = (h==0)?m0:(h==1)?m1:(h==2)?m2:m3;
  float acc = 0.f, den = 0.f;
  for(int i=beg; i<end; i++){
    int e = elist[i];
    float v  = EdgeV[(size_t)e*64 + ln];
    float a  = Attn[(size_t)e*4 + h];
    float ex = __expf(a - mh);
    acc = fmaf(ex, v, acc);
    den += ex;
  }
  Upd[(size_t)n*64 + ln] = acc / (den + 1e-9f);
}

// ---------------- node output GEMMs: thread-per-(node,channel) -------------
__global__ __launch_bounds__(256) void k_nodeout(
    const float* __restrict__ Upd, const float* __restrict__ tfn,
    const float* __restrict__ Wos, const float* __restrict__ Wov,
    const float* __restrict__ Wss, const float* __restrict__ Wsv,
    float* __restrict__ Pre){
  int idx = blockIdx.x*256 + threadIdx.x;
  if(idx >= NN*40) return;
  int n = idx/40, c = idx - n*40;
  const float* up = Upd + (size_t)n*64;
  const float* tp = tfn + (size_t)n*40;
  float out;
  if(c < 16){
    float a=0.f, b=0.f;
    #pragma unroll
    for(int u=0;u<16;u++){
      a = fmaf(up[u], Wos[u*16+c], a);
      b = fmaf(tp[u], Wss[u*16+c], b);
    }
    out = (a+b)*0.25f;
  } else {
    int w = (c-16)/3, i = (c-16)%3;
    float a=0.f, b=0.f;
    #pragma unroll
    for(int u=0;u<16;u++) a = fmaf(up[16+u*3+i], Wov[u*8+w], a);
    #pragma unroll
    for(int u=0;u<8;u++)  b = fmaf(tp[16+u*3+i], Wsv[u*8+w], b);
    out = a*0.25f + b*INV_S8;
  }
  Pre[idx] = out;
}

// ---------------- BN stats: 24 blocks, column-streaming, no atomics --------
__global__ __launch_bounds__(256) void k_stats(
    const float* __restrict__ Pre, float* __restrict__ Stats){
  int b = blockIdx.x;              // 0..15 scalar cols, 16..23 vector groups
  int lane = threadIdx.x & 63, wave = threadIdx.x >> 6;
  float s1 = 0.f, s2 = 0.f;
  if(b < 16){
    for(int n = threadIdx.x; n < NN; n += 256){
      float x = Pre[(size_t)n*40 + b];
      s1 += x; s2 += x*x;
    }
  } else {
    int w3 = 16 + (b-16)*3;
    for(int n = threadIdx.x; n < NN; n += 256){
      const float* p = Pre + (size_t)n*40 + w3;
      s1 += p[0]*p[0] + p[1]*p[1] + p[2]*p[2];
    }
  }
  #pragma unroll
  for(int off=1; off<64; off<<=1){
    s1 += __shfl_xor(s1, off);
    s2 += __shfl_xor(s2, off);
  }
  __shared__ float ws1[4], ws2[4];
  if(lane == 0){ ws1[wave] = s1; ws2[wave] = s2; }
  __syncthreads();
  if(threadIdx.x == 0){
    float t1 = ws1[0]+ws1[1]+ws1[2]+ws1[3];
    float t2 = ws2[0]+ws2[1]+ws2[2]+ws2[3];
    if(b < 16){ Stats[b] = t1; Stats[16+b] = t2; }
    else        Stats[32+(b-16)] = t1;
  }
}

// ---------------- finalize BN + write output -------------------------------
__global__ __launch_bounds__(256) void k_final(
    const float* __restrict__ Pre, const float* __restrict__ Stats,
    const float* __restrict__ bnws, const float* __restrict__ bnbs,
    const float* __restrict__ bnwv, float* __restrict__ Out){
  int idx = blockIdx.x*256 + threadIdx.x;
  if(idx >= NN*40) return;
  int n = idx/40, c = idx - n*40;
  float x = Pre[idx];
  float r;
  if(c < 16){
    float mu  = Stats[c]    * (1.f/NN);
    float var = Stats[16+c] * (1.f/NN) - mu*mu;
    r = (x - mu) / sqrtf(var + 1e-5f) * bnws[c] + bnbs[c];
  } else {
    int w = (c-16)/3;
    float n2 = Stats[32+w] * (1.f/NN);
    r = x / sqrtf(n2 + 1e-5f) * bnwv[w];
  }
  Out[idx] = r;
}

extern "C" void kernel_launch(void* const* d_in, const int* in_sizes, int n_in,
                              void* d_out, int out_size, void* d_ws, size_t ws_size,
                              hipStream_t stream){
  const float* frame = (const float*)d_in[0];
  const float* rot   = (const float*)d_in[1];
  const float* trans = (const float*)d_in[2];
  const float* tfn   = (const float*)d_in[3];
  const float* ef    = (const float*)d_in[4];
  const float* esh   = (const float*)d_in[5];
  const int*   ei    = (const int*)  d_in[6];
  const float* Wf0   = (const float*)d_in[7];
  const float* bf0   = (const float*)d_in[8];
  const float* Wf1   = (const float*)d_in[9];
  const float* bf1   = (const float*)d_in[10];
  const float* Wgs   = (const float*)d_in[11];
  const float* Wgv   = (const float*)d_in[12];
  const float* Wqs   = (const float*)d_in[13];
  const float* Wqv   = (const float*)d_in[14];
  const float* Wk1   = (const float*)d_in[15];
  const float* bk1   = (const float*)d_in[16];
  const float* Wk2   = (const float*)d_in[17];
  const float* bk2   = (const float*)d_in[18];
  const float* Wv1   = (const float*)d_in[19];
  const float* bv1   = (const float*)d_in[20];
  const float* Wv2   = (const float*)d_in[21];
  const float* bv2   = (const float*)d_in[22];
  const float* Wos   = (const float*)d_in[23];
  const float* Wov   = (const float*)d_in[24];
  const float* Wss   = (const float*)d_in[25];
  const float* Wsv   = (const float*)d_in[26];
  const float* bnws  = (const float*)d_in[27];
  const float* bnbs  = (const float*)d_in[28];
  const float* bnwv  = (const float*)d_in[29];

  float* ws   = (float*)d_ws;
  float* f0f1 = ws;                                   // N*160 (unused now)
  float* Gs   = f0f1 + (size_t)NN*160;                // N*16
  float* Gv   = Gs   + (size_t)NN*16;                 // N*24
  float* Qs   = Gv   + (size_t)NN*24;                 // N*16
  float* Qv   = Qs   + (size_t)NN*16;                 // N*24
  float* Attn = Qv   + (size_t)NN*24;                 // E*4
  float* Pre  = Attn + (size_t)EE*4;                  // N*40
  float* Upd  = Pre  + (size_t)NN*40;                 // N*64
  float* EdgeV= Upd  + (size_t)NN*64;                 // E*64
  float* Stats= EdgeV+ (size_t)EE*64;                 // 64 floats
  int*   cnt  = (int*)(Stats + 64);                   // N+16   (zeroed)
  int*   ofs  = cnt + (NN+16);                        // N+16 (use [0..N])
  int*   fill = ofs + (NN+16);                        // N+16
  int*   elist= fill + (NN+16);                       // E
  float* biasV= (float*)(elist + EE);                 // 896  (16B-aligned)
  float* biasK= biasV + 896;                          // 640
  unsigned short* A2rV = (unsigned short*)(biasK + 640);  // 896*32
  unsigned short* A2rK = A2rV + 896*32;                   // 640*32

  hipMemsetAsync(cnt, 0, (NN + 16)*sizeof(int), stream);

  k_node    <<<dim3(NN),              192, 0, stream>>>(frame, Wf0, bf0, Wf1, bf1,
                                                        rot, trans, tfn,
                                                        Wgs, Wgv, Wqs, Wqv,
                                                        Gs, Gv, Qs, Qv);
  k_prepw   <<<dim3(198),             256, 0, stream>>>(Wk2, bk2, Wv2, bv2, A2rK, A2rV, biasK, biasV);
  k_hist    <<<dim3((EE+255)/256),    256, 0, stream>>>(ei, cnt);
  k_scan    <<<dim3(1),               256, 0, stream>>>(cnt, ofs, fill);
  k_scatter <<<dim3((EE+255)/256),    256, 0, stream>>>(ei, fill, elist);
  k_edge_vk <<<dim3(2*NVB),           128, 0, stream>>>(ei, esh, ef, Gs, Gv, Qs, Qv,
                                                        Wv1, bv1, Wk1, bk1,
                                                        A2rV, biasV, A2rK, biasK,
                                                        EdgeV, Attn);
  k_reduce  <<<dim3((NN+3)/4),        256, 0, stream>>>(ofs, elist, Attn, EdgeV, Upd);
  k_nodeout <<<dim3((NN*40+255)/256), 256, 0, stream>>>(Upd, tfn, Wos, Wov, Wss, Wsv, Pre);
  k_stats   <<<dim3(24),              256, 0, stream>>>(Pre, Stats);
  k_final   <<<dim3((NN*40+255)/256), 256, 0, stream>>>(Pre, Stats, bnws, bnbs, bnwv, (float*)d_out);
}

// Round 18
// 252.674 us; speedup vs baseline: 1.0622x; 1.0195x over previous
//
#include <hip/hip_runtime.h>
#include <hip/hip_bf16.h>
#include <math.h>

#define NN 10000
#define EE 160000
#define CSZ 128
#define NVB (EE/128)   // 1250 V-blocks, then 1250 K-blocks

#define INV_S8  0.35355339059327373f   // 1/sqrt(8)
#define INV_S32 0.17677669529663687f   // 1/sqrt(32)
#define INV_S2  0.7071067811865476f    // 1/sqrt(2)
#define INV_S3  0.5773502691896258f    // 1/sqrt(3)

typedef short s16x8 __attribute__((ext_vector_type(8)));
typedef float f32x4 __attribute__((ext_vector_type(4)));

__device__ __forceinline__ unsigned short f2bf(float f){
  __hip_bfloat16 h = __float2bfloat16(f);
  return *reinterpret_cast<unsigned short*>(&h);
}

// ---------------- Fused node kernel: f0/f1 GEMM + rotate + gs/gv/qs/qv -----
__global__ __launch_bounds__(192) void k_node(
    const float* __restrict__ frame,
    const float* __restrict__ Wf0, const float* __restrict__ bf0,
    const float* __restrict__ Wf1, const float* __restrict__ bf1,
    const float* __restrict__ rot, const float* __restrict__ trans,
    const float* __restrict__ tfn,
    const float* __restrict__ Wgs, const float* __restrict__ Wgv,
    const float* __restrict__ Wqs, const float* __restrict__ Wqv,
    float* __restrict__ Gs, float* __restrict__ Gv,
    float* __restrict__ Qs, float* __restrict__ Qv){
  __shared__ float ff[160];
  __shared__ float f1r[32][3];
  int n = blockIdx.x;
  int t = threadIdx.x;
  if(t < 160){
    bool is0 = t < 64;
    int cc = is0 ? t : (t-64);
    const float* W = is0 ? Wf0 : Wf1;
    int ldw = is0 ? 64 : 96;
    float acc = is0 ? bf0[cc] : bf1[cc];
    const float* fp = frame + (size_t)n*CSZ;
    #pragma unroll 8
    for(int k=0;k<CSZ;k++)
      acc = fmaf(fp[k], W[k*ldw + cc], acc);
    ff[t] = acc;
  }
  __syncthreads();
  if(t < 32){
    float v0 = ff[64+t*3+0], v1 = ff[64+t*3+1], v2 = ff[64+t*3+2];
    const float* R = rot + (size_t)n*9;
    const float* tr = trans + (size_t)n*3;
    f1r[t][0] = R[0]*v0 + R[1]*v1 + R[2]*v2 + tr[0];
    f1r[t][1] = R[3]*v0 + R[4]*v1 + R[5]*v2 + tr[1];
    f1r[t][2] = R[6]*v0 + R[7]*v1 + R[8]*v2 + tr[2];
  }
  __syncthreads();
  if(t < 16){
    float a = 0.f;
    #pragma unroll
    for(int u=0;u<64;u++) a = fmaf(ff[u], Wgs[u*16+t], a);
    Gs[(size_t)n*16+t] = a * 0.125f;
  } else if(t < 40){
    int idx = t-16, w = idx/3, i = idx%3; float a = 0.f;
    #pragma unroll
    for(int u=0;u<32;u++) a = fmaf(f1r[u][i], Wgv[u*8+w], a);
    Gv[(size_t)n*24+idx] = a * INV_S32;
  } else if(t < 56){
    int w = t-40; float a = 0.f;
    #pragma unroll
    for(int u=0;u<16;u++) a = fmaf(tfn[(size_t)n*40+u], Wqs[u*16+w], a);
    Qs[(size_t)n*16+w] = a * 0.25f;
  } else if(t < 80){
    int idx = t-56, w = idx/3, i = idx%3; float a = 0.f;
    #pragma unroll
    for(int u=0;u<8;u++) a = fmaf(tfn[(size_t)n*40+16+u*3+i], Wqv[u*8+w], a);
    Qv[(size_t)n*24+idx] = a * INV_S8;
  }
}

// ---------------- CSR build ------------------------------------------------
__global__ __launch_bounds__(256) void k_hist(const int* __restrict__ ei, int* __restrict__ cnt){
  int e = blockIdx.x*256 + threadIdx.x;
  if(e < EE) atomicAdd(&cnt[ei[EE + e]], 1);
}

__global__ __launch_bounds__(256) void k_scan(const int* __restrict__ cnt,
                                              int* __restrict__ ofs, int* __restrict__ fill){
  __shared__ int tsum[256];
  int t = threadIdx.x;
  const int CH = (NN + 255)/256;
  int base = t*CH;
  int s = 0;
  for(int i=0;i<CH;i++){ int idx=base+i; if(idx<NN) s += cnt[idx]; }
  tsum[t] = s;
  __syncthreads();
  for(int off=1; off<256; off<<=1){
    int v = (t>=off)? tsum[t-off] : 0;
    __syncthreads();
    tsum[t] += v;
    __syncthreads();
  }
  int run = (t==0)? 0 : tsum[t-1];
  for(int i=0;i<CH;i++){
    int idx = base+i;
    if(idx < NN){ ofs[idx] = run; fill[idx] = run; run += cnt[idx]; }
  }
  if(t==255) ofs[NN] = tsum[255];
}

__global__ __launch_bounds__(256) void k_scatter(const int* __restrict__ ei,
                                                 int* __restrict__ fill, int* __restrict__ elist){
  int e = blockIdx.x*256 + threadIdx.x;
  if(e >= EE) return;
  int src = ei[EE + e];
  int pos = atomicAdd(&fill[src], 1);
  elist[pos] = e;
}

// ---------------- Weight reshape: W2 -> MFMA A-fragment order, bf16 --------
__global__ __launch_bounds__(256) void k_prepw(
    const float* __restrict__ Wk2, const float* __restrict__ bk2,
    const float* __restrict__ Wv2, const float* __restrict__ bv2,
    unsigned short* __restrict__ A2rK, unsigned short* __restrict__ A2rV,
    float* __restrict__ biasK, float* __restrict__ biasV){
  int tid = blockIdx.x*256 + threadIdx.x;
  const int NV = 896*32, NK = 640*32;
  if(tid < NV){
    int c = tid>>5, h = tid&31;
    float s = (c<384)? INV_S2 : INV_S3;
    A2rV[(c>>4)*512 + (c&15)*32 + h] = f2bf(Wv2[h*896+c]*s);
  } else if(tid < NV+NK){
    int i = tid - NV; int c = i>>5, h = i&31;
    float s = (c<384)? INV_S2 : INV_S3;
    A2rK[(c>>4)*512 + (c&15)*32 + h] = f2bf(Wk2[h*640+c]*s);
  } else if(tid < NV+NK+896){
    int c = tid - (NV+NK);
    biasV[c] = bv2[c] * ((c<384)? INV_S2 : INV_S3);
  } else if(tid < NV+NK+896+640){
    int c = tid - (NV+NK+896);
    biasK[c] = bk2[c] * ((c<384)? INV_S2 : INV_S3);
  }
}

// hidden MLP -> LDS fragments -> af[4] regs (B-operand frags). hL overlays F.
#define HID_TO_FRAGS(W1, b1) { \
  unsigned short* hL = (unsigned short*)&F[0][0]; \
  float efv[32]; \
  const float4* efp = (const float4*)(ef + (size_t)e*32); \
  _Pragma("unroll") \
  for(int q=0;q<8;q++){ float4 t=efp[q]; efv[q*4]=t.x; efv[q*4+1]=t.y; efv[q*4+2]=t.z; efv[q*4+3]=t.w; } \
  float hd[32]; \
  _Pragma("unroll") \
  for(int h=0;h<32;h++) hd[h] = b1[h]; \
  _Pragma("unroll") \
  for(int k=0;k<32;k++){ \
    float ekv = efv[k]; \
    _Pragma("unroll") \
    for(int h=0;h<32;h++) hd[h] = fmaf(ekv, W1[k*32+h], hd[h]); \
  } \
  _Pragma("unroll") \
  for(int gg=0;gg<4;gg++){ \
    s16x8 p; \
    _Pragma("unroll") \
    for(int j=0;j<8;j++) p[j] = (short)f2bf(fmaxf(hd[gg*8+j], 0.f)); \
    *(s16x8*)&hL[((g*4+gg)*16 + e16)*8] = p; \
  } \
  _Pragma("unroll") \
  for(int tt=0;tt<4;tt++) \
    af[tt] = *(const s16x8*)&hL[((tt*4 + g)*16 + e16)*8]; }

// features -> LDS (rows 0..15 fsn=Gs*0.25, rows 16..39 fv) + sh via shfl
#define STAGE_FEATURES() { \
  const float4* g4 = (const float4*)(Gs + (size_t)dst*16); \
  _Pragma("unroll") \
  for(int q=0;q<4;q++){ float4 t = g4[q]; \
    F[q*4+0][lane]=t.x*0.25f; F[q*4+1][lane]=t.y*0.25f; \
    F[q*4+2][lane]=t.z*0.25f; F[q*4+3][lane]=t.w*0.25f; } \
  const float4* v4 = (const float4*)(Gv + (size_t)dst*24); \
  _Pragma("unroll") \
  for(int q=0;q<6;q++){ float4 t = v4[q]; \
    F[16+q*4+0][lane]=t.x; F[16+q*4+1][lane]=t.y; \
    F[16+q*4+2][lane]=t.z; F[16+q*4+3][lane]=t.w; } \
  _Pragma("unroll") \
  for(int tt=0;tt<4;tt++){ \
    int sl = tt*16 + e16; \
    shs_t[tt]  = __shfl(shs, sl); \
    sv_t[tt][0]= __shfl(sv0, sl); \
    sv_t[tt][1]= __shfl(sv1, sl); \
    sv_t[tt][2]= __shfl(sv2, sl); \
    shsI8_t[tt]= shs_t[tt]*INV_S8; \
  } }

// per-ntile MFMA: load weight frag + bias, 4 MFMAs into acc4[tt]
#define NTILE_MFMA(A2r, bias, NT) \
  s16x8 Aw = *(const s16x8*)&A2r[(NT)*512 + e16*32 + g*8]; \
  float4 b4 = *(const float4*)&bias[(NT)*16 + g*4]; \
  f32x4 acc4[4]; \
  _Pragma("unroll") \
  for(int tt=0; tt<4; ++tt){ \
    f32x4 a0 = {b4.x, b4.y, b4.z, b4.w}; \
    acc4[tt] = __builtin_amdgcn_mfma_f32_16x16x32_bf16(Aw, af[tt], a0, 0, 0, 0); \
  }

// ---------------- Edge V body: CSR-ordered (e = elist[p], out at p) --------
__device__ __forceinline__ void edge_v_body(
    int blk, float (*F)[64],
    const int* __restrict__ ei, const float* __restrict__ esh,
    const float* __restrict__ ef, const int* __restrict__ elist,
    const float* __restrict__ Gs, const float* __restrict__ Gv,
    const float* __restrict__ Wv1, const float* __restrict__ bv1,
    const unsigned short* __restrict__ A2rV, const float* __restrict__ biasV,
    float* __restrict__ EdgeV){
  int wave = threadIdx.x >> 6, lane = threadIdx.x & 63;
  int ebase = blk*128 + wave*64;
  int e = elist[ebase + lane];          // gather actual edge id
  int e16 = lane & 15, g = lane >> 4;

  int dst = ei[e];
  float4 sh4 = *(const float4*)(esh + (size_t)e*4);
  float shs = sh4.x, sv0 = sh4.y, sv1 = sh4.z, sv2 = sh4.w;

  s16x8 af[4];
  HID_TO_FRAGS(Wv1, bv1);
  float shs_t[4], sv_t[4][3], shsI8_t[4];
  STAGE_FEATURES();

  // ---- path A: ntiles 0..15 ----
  float A16[4][4] = {};
  #pragma unroll 1
  for(int ntile=0; ntile<16; ++ntile){
    NTILE_MFMA(A2rV, biasV, ntile);
    #pragma unroll
    for(int tt=0; tt<4; ++tt){
      float f = F[ntile][tt*16+e16] * shs_t[tt];
      #pragma unroll
      for(int r=0;r<4;r++) A16[tt][r] = fmaf(f, acc4[tt][r], A16[tt][r]);
    }
  }
  // ---- path B: ntiles 16..23 ----
  #pragma unroll 1
  for(int ntile=16; ntile<24; ++ntile){
    NTILE_MFMA(A2rV, biasV, ntile);
    int u3 = 16 + (ntile-16)*3;
    #pragma unroll
    for(int tt=0; tt<4; ++tt){
      int eL = tt*16+e16;
      float f = (F[u3+0][eL]*sv_t[tt][0] + F[u3+1][eL]*sv_t[tt][1]
               + F[u3+2][eL]*sv_t[tt][2]) * INV_S8;
      #pragma unroll
      for(int r=0;r<4;r++) A16[tt][r] = fmaf(f, acc4[tt][r], A16[tt][r]);
    }
  }
  #pragma unroll
  for(int tt=0; tt<4; ++tt){
    int eo = ebase + tt*16 + e16;       // CSR position
    *(float4*)(EdgeV + (size_t)eo*64 + g*4) =
        make_float4(A16[tt][0], A16[tt][1], A16[tt][2], A16[tt][3]);
  }

  // ---- paths C+D+E: ntiles 24..55 -> vector outputs VV ----
  float VV[4][4][3] = {};
  #pragma unroll 1
  for(int ntile=24; ntile<40; ++ntile){        // path C
    NTILE_MFMA(A2rV, biasV, ntile);
    #pragma unroll
    for(int tt=0; tt<4; ++tt){
      float f = F[ntile-24][tt*16+e16];
      #pragma unroll
      for(int r=0;r<4;r++){
        float c = f*acc4[tt][r];
        VV[tt][r][0] = fmaf(c, sv_t[tt][0], VV[tt][r][0]);
        VV[tt][r][1] = fmaf(c, sv_t[tt][1], VV[tt][r][1]);
        VV[tt][r][2] = fmaf(c, sv_t[tt][2], VV[tt][r][2]);
      }
    }
  }
  #pragma unroll 1
  for(int ntile=40; ntile<48; ++ntile){        // path D
    NTILE_MFMA(A2rV, biasV, ntile);
    int u3 = 16 + (ntile-40)*3;
    #pragma unroll
    for(int tt=0; tt<4; ++tt){
      int eL = tt*16+e16;
      float f0 = F[u3+0][eL]*shsI8_t[tt];
      float f1 = F[u3+1][eL]*shsI8_t[tt];
      float f2 = F[u3+2][eL]*shsI8_t[tt];
      #pragma unroll
      for(int r=0;r<4;r++){
        VV[tt][r][0] = fmaf(f0, acc4[tt][r], VV[tt][r][0]);
        VV[tt][r][1] = fmaf(f1, acc4[tt][r], VV[tt][r][1]);
        VV[tt][r][2] = fmaf(f2, acc4[tt][r], VV[tt][r][2]);
      }
    }
  }
  #pragma unroll 1
  for(int ntile=48; ntile<56; ++ntile){        // path E
    NTILE_MFMA(A2rV, biasV, ntile);
    int u3 = 16 + (ntile-48)*3;
    #pragma unroll
    for(int tt=0; tt<4; ++tt){
      int eL = tt*16+e16;
      float a0 = F[u3+0][eL], a1 = F[u3+1][eL], a2 = F[u3+2][eL];
      float x0 = (a1*sv_t[tt][2] - a2*sv_t[tt][1])*INV_S8;
      float x1 = (a2*sv_t[tt][0] - a0*sv_t[tt][2])*INV_S8;
      float x2 = (a0*sv_t[tt][1] - a1*sv_t[tt][0])*INV_S8;
      #pragma unroll
      for(int r=0;r<4;r++){
        VV[tt][r][0] = fmaf(x0, acc4[tt][r], VV[tt][r][0]);
        VV[tt][r][1] = fmaf(x1, acc4[tt][r], VV[tt][r][1]);
        VV[tt][r][2] = fmaf(x2, acc4[tt][r], VV[tt][r][2]);
      }
    }
  }
  #pragma unroll
  for(int tt=0; tt<4; ++tt){
    int eo = ebase + tt*16 + e16;
    float* op = EdgeV + (size_t)eo*64 + 16 + g*12;
    float v[12] = {VV[tt][0][0],VV[tt][0][1],VV[tt][0][2],
                   VV[tt][1][0],VV[tt][1][1],VV[tt][1][2],
                   VV[tt][2][0],VV[tt][2][1],VV[tt][2][2],
                   VV[tt][3][0],VV[tt][3][1],VV[tt][3][2]};
    #pragma unroll
    for(int k=0;k<6;k++)
      *(float2*)(op + k*2) = make_float2(v[k*2], v[k*2+1]);
  }
}

// ---------------- Edge K body: CSR-ordered (e = elist[p], out at p) --------
__device__ __forceinline__ void edge_k_body(
    int blk, float (*F)[64],
    const int* __restrict__ ei, const float* __restrict__ esh,
    const float* __restrict__ ef, const int* __restrict__ elist,
    const float* __restrict__ Gs, const float* __restrict__ Gv,
    const float* __restrict__ Qs, const float* __restrict__ Qv,
    const float* __restrict__ Wk1, const float* __restrict__ bk1,
    const unsigned short* __restrict__ A2rK, const float* __restrict__ biasK,
    float* __restrict__ Attn){
  int wave = threadIdx.x >> 6, lane = threadIdx.x & 63;
  int ebase = blk*128 + wave*64;
  int e = elist[ebase + lane];
  int e16 = lane & 15, g = lane >> 4;

  int dst = ei[e];
  float4 sh4 = *(const float4*)(esh + (size_t)e*4);
  float shs = sh4.x, sv0 = sh4.y, sv1 = sh4.z, sv2 = sh4.w;

  s16x8 af[4];
  HID_TO_FRAGS(Wk1, bk1);
  float shs_t[4], sv_t[4][3], shsI8_t[4];
  STAGE_FEATURES();

  // ---- path A: ntiles 0..15 ----
  float KS[4][4] = {};
  #pragma unroll 1
  for(int ntile=0; ntile<16; ++ntile){
    NTILE_MFMA(A2rK, biasK, ntile);
    #pragma unroll
    for(int tt=0; tt<4; ++tt){
      float f = F[ntile][tt*16+e16] * shs_t[tt];
      #pragma unroll
      for(int r=0;r<4;r++) KS[tt][r] = fmaf(f, acc4[tt][r], KS[tt][r]);
    }
  }
  // ---- path B: ntiles 16..23 ----
  #pragma unroll 1
  for(int ntile=16; ntile<24; ++ntile){
    NTILE_MFMA(A2rK, biasK, ntile);
    int u3 = 16 + (ntile-16)*3;
    #pragma unroll
    for(int tt=0; tt<4; ++tt){
      int eL = tt*16+e16;
      float f = (F[u3+0][eL]*sv_t[tt][0] + F[u3+1][eL]*sv_t[tt][1]
               + F[u3+2][eL]*sv_t[tt][2]) * INV_S8;
      #pragma unroll
      for(int r=0;r<4;r++) KS[tt][r] = fmaf(f, acc4[tt][r], KS[tt][r]);
    }
  }
  // fold KS -> per-lane scalar dot (head h = g); KS dies
  int src_t[4]; float ksd[4];
  #pragma unroll
  for(int tt=0; tt<4; ++tt){
    int ep = elist[ebase + tt*16 + e16];   // actual edge at CSR pos
    src_t[tt] = ei[EE + ep];
    float4 q4 = *(const float4*)(Qs + (size_t)src_t[tt]*16 + g*4);
    ksd[tt] = q4.x*KS[tt][0] + q4.y*KS[tt][1] + q4.z*KS[tt][2] + q4.w*KS[tt][3];
  }

  // ---- paths C+D+E: ntiles 24..39 -> KV (w = (g&1)*4+r, u-halves by g>>1) --
  float KV[4][4][3] = {};
  int gh = g >> 1;
  #pragma unroll 1
  for(int ntile=24; ntile<32; ++ntile){        // path C
    NTILE_MFMA(A2rK, biasK, ntile);
    int fr = (ntile-24)*2 + gh;
    #pragma unroll
    for(int tt=0; tt<4; ++tt){
      float f = F[fr][tt*16+e16];
      #pragma unroll
      for(int r=0;r<4;r++){
        float c = f*acc4[tt][r];
        KV[tt][r][0] = fmaf(c, sv_t[tt][0], KV[tt][r][0]);
        KV[tt][r][1] = fmaf(c, sv_t[tt][1], KV[tt][r][1]);
        KV[tt][r][2] = fmaf(c, sv_t[tt][2], KV[tt][r][2]);
      }
    }
  }
  #pragma unroll 1
  for(int ntile=32; ntile<36; ++ntile){        // path D
    NTILE_MFMA(A2rK, biasK, ntile);
    int u3 = 16 + ((ntile-32)*2 + gh)*3;
    #pragma unroll
    for(int tt=0; tt<4; ++tt){
      int eL = tt*16+e16;
      float f0 = F[u3+0][eL]*shsI8_t[tt];
      float f1 = F[u3+1][eL]*shsI8_t[tt];
      float f2 = F[u3+2][eL]*shsI8_t[tt];
      #pragma unroll
      for(int r=0;r<4;r++){
        KV[tt][r][0] = fmaf(f0, acc4[tt][r], KV[tt][r][0]);
        KV[tt][r][1] = fmaf(f1, acc4[tt][r], KV[tt][r][1]);
        KV[tt][r][2] = fmaf(f2, acc4[tt][r], KV[tt][r][2]);
      }
    }
  }
  #pragma unroll 1
  for(int ntile=36; ntile<40; ++ntile){        // path E
    NTILE_MFMA(A2rK, biasK, ntile);
    int u3 = 16 + ((ntile-36)*2 + gh)*3;
    #pragma unroll
    for(int tt=0; tt<4; ++tt){
      int eL = tt*16+e16;
      float a0 = F[u3+0][eL], a1 = F[u3+1][eL], a2 = F[u3+2][eL];
      float x0 = (a1*sv_t[tt][2] - a2*sv_t[tt][1])*INV_S8;
      float x1 = (a2*sv_t[tt][0] - a0*sv_t[tt][2])*INV_S8;
      float x2 = (a0*sv_t[tt][1] - a1*sv_t[tt][0])*INV_S8;
      #pragma unroll
      for(int r=0;r<4;r++){
        KV[tt][r][0] = fmaf(x0, acc4[tt][r], KV[tt][r][0]);
        KV[tt][r][1] = fmaf(x1, acc4[tt][r], KV[tt][r][1]);
        KV[tt][r][2] = fmaf(x2, acc4[tt][r], KV[tt][r][2]);
      }
    }
  }
  // ---- final: qv dot + cross-group reduce + write logits ----
  int godd = g & 1;
  #pragma unroll
  for(int tt=0; tt<4; ++tt){
    const float* qvp = Qv + (size_t)src_t[tt]*24 + godd*12;
    float4 qa = *(const float4*)(qvp);
    float4 qb = *(const float4*)(qvp+4);
    float4 qc = *(const float4*)(qvp+8);
    float kvs0 = qa.x*KV[tt][0][0] + qa.y*KV[tt][0][1] + qa.z*KV[tt][0][2]
               + qa.w*KV[tt][1][0] + qb.x*KV[tt][1][1] + qb.y*KV[tt][1][2];
    float kvs1 = qb.z*KV[tt][2][0] + qb.w*KV[tt][2][1] + qc.x*KV[tt][2][2]
               + qc.y*KV[tt][3][0] + qc.z*KV[tt][3][1] + qc.w*KV[tt][3][2];
    float p0 = ((g==0)? ksd[tt] : 0.f) + (godd? 0.f : kvs0);
    float p1 = ((g==1)? ksd[tt] : 0.f) + (godd? 0.f : kvs1);
    float p2 = ((g==2)? ksd[tt] : 0.f) + (godd? kvs0 : 0.f);
    float p3 = ((g==3)? ksd[tt] : 0.f) + (godd? kvs1 : 0.f);
    p0 += __shfl_xor(p0,16); p0 += __shfl_xor(p0,32);
    p1 += __shfl_xor(p1,16); p1 += __shfl_xor(p1,32);
    p2 += __shfl_xor(p2,16); p2 += __shfl_xor(p2,32);
    p3 += __shfl_xor(p3,16); p3 += __shfl_xor(p3,32);
    if(lane < 16){
      int eo = ebase + tt*16 + lane;      // CSR position
      *(float4*)(Attn + (size_t)eo*4) = make_float4(p0, p1, p2, p3);
    }
  }
}

// ---------------- Merged edge kernel: V-blocks then K-blocks, one launch ---
__global__ __launch_bounds__(128) void k_edge_vk(
    const int* __restrict__ ei, const float* __restrict__ esh,
    const float* __restrict__ ef, const int* __restrict__ elist,
    const float* __restrict__ Gs, const float* __restrict__ Gv,
    const float* __restrict__ Qs, const float* __restrict__ Qv,
    const float* __restrict__ Wv1, const float* __restrict__ bv1,
    const float* __restrict__ Wk1, const float* __restrict__ bk1,
    const unsigned short* __restrict__ A2rV, const float* __restrict__ biasV,
    const unsigned short* __restrict__ A2rK, const float* __restrict__ biasK,
    float* __restrict__ EdgeV, float* __restrict__ Attn){
  __shared__ float featAll[2][40][64];
  float (*F)[64] = featAll[threadIdx.x >> 6];
  if(blockIdx.x < NVB)
    edge_v_body(blockIdx.x, F, ei, esh, ef, elist, Gs, Gv, Wv1, bv1, A2rV, biasV, EdgeV);
  else
    edge_k_body(blockIdx.x - NVB, F, ei, esh, ef, elist, Gs, Gv, Qs, Qv, Wk1, bk1, A2rK, biasK, Attn);
}

// ---------------- per-node softmax + weighted sum (streaming, no gather) ---
__global__ __launch_bounds__(256) void k_reduce(
    const int* __restrict__ ofs,
    const float* __restrict__ Attn, const float* __restrict__ EdgeV,
    float* __restrict__ Upd){
  int wid = threadIdx.x >> 6, ln = threadIdx.x & 63;
  int n = blockIdx.x*4 + wid;
  if(n >= NN) return;
  int beg = ofs[n], end = ofs[n+1];
  float m0=-3.4e38f, m1=-3.4e38f, m2=-3.4e38f, m3=-3.4e38f;
  for(int i=beg+ln; i<end; i+=64){
    float4 a = *(const float4*)(Attn + (size_t)i*4);
    m0=fmaxf(m0,a.x); m1=fmaxf(m1,a.y); m2=fmaxf(m2,a.z); m3=fmaxf(m3,a.w);
  }
  #pragma unroll
  for(int off=1; off<64; off<<=1){
    m0=fmaxf(m0,__shfl_xor(m0,off)); m1=fmaxf(m1,__shfl_xor(m1,off));
    m2=fmaxf(m2,__shfl_xor(m2,off)); m3=fmaxf(m3,__shfl_xor(m3,off));
  }
  int h = (ln < 16) ? (ln >> 2) : (((ln - 16)/3) >> 2);
  float mh = (h==0)?m0:(h==1)?m1:(h==2)?m2:m3;
  float acc = 0.f, den = 0.f;
  for(int i=beg; i<end; i++){
    float v  = EdgeV[(size_t)i*64 + ln];
    float a  = Attn[(size_t)i*4 + h];
    float ex = __expf(a - mh);
    acc = fmaf(ex, v, acc);
    den += ex;
  }
  Upd[(size_t)n*64 + ln] = acc / (den + 1e-9f);
}

// ---------------- node output GEMMs: thread-per-(node,channel) -------------
__global__ __launch_bounds__(256) void k_nodeout(
    const float* __restrict__ Upd, const float* __restrict__ tfn,
    const float* __restrict__ Wos, const float* __restrict__ Wov,
    const float* __restrict__ Wss, const float* __restrict__ Wsv,
    float* __restrict__ Pre){
  int idx = blockIdx.x*256 + threadIdx.x;
  if(idx >= NN*40) return;
  int n = idx/40, c = idx - n*40;
  const float* up = Upd + (size_t)n*64;
  const float* tp = tfn + (size_t)n*40;
  float out;
  if(c < 16){
    float a=0.f, b=0.f;
    #pragma unroll
    for(int u=0;u<16;u++){
      a = fmaf(up[u], Wos[u*16+c], a);
      b = fmaf(tp[u], Wss[u*16+c], b);
    }
    out = (a+b)*0.25f;
  } else {
    int w = (c-16)/3, i = (c-16)%3;
    float a=0.f, b=0.f;
    #pragma unroll
    for(int u=0;u<16;u++) a = fmaf(up[16+u*3+i], Wov[u*8+w], a);
    #pragma unroll
    for(int u=0;u<8;u++)  b = fmaf(tp[16+u*3+i], Wsv[u*8+w], b);
    out = a*0.25f + b*INV_S8;
  }
  Pre[idx] = out;
}

// ---------------- BN stats: 24 blocks, column-streaming, no atomics --------
__global__ __launch_bounds__(256) void k_stats(
    const float* __restrict__ Pre, float* __restrict__ Stats){
  int b = blockIdx.x;              // 0..15 scalar cols, 16..23 vector groups
  int lane = threadIdx.x & 63, wave = threadIdx.x >> 6;
  float s1 = 0.f, s2 = 0.f;
  if(b < 16){
    for(int n = threadIdx.x; n < NN; n += 256){
      float x = Pre[(size_t)n*40 + b];
      s1 += x; s2 += x*x;
    }
  } else {
    int w3 = 16 + (b-16)*3;
    for(int n = threadIdx.x; n < NN; n += 256){
      const float* p = Pre + (size_t)n*40 + w3;
      s1 += p[0]*p[0] + p[1]*p[1] + p[2]*p[2];
    }
  }
  #pragma unroll
  for(int off=1; off<64; off<<=1){
    s1 += __shfl_xor(s1, off);
    s2 += __shfl_xor(s2, off);
  }
  __shared__ float ws1[4], ws2[4];
  if(lane == 0){ ws1[wave] = s1; ws2[wave] = s2; }
  __syncthreads();
  if(threadIdx.x == 0){
    float t1 = ws1[0]+ws1[1]+ws1[2]+ws1[3];
    float t2 = ws2[0]+ws2[1]+ws2[2]+ws2[3];
    if(b < 16){ Stats[b] = t1; Stats[16+b] = t2; }
    else        Stats[32+(b-16)] = t1;
  }
}

// ---------------- finalize BN + write output -------------------------------
__global__ __launch_bounds__(256) void k_final(
    const float* __restrict__ Pre, const float* __restrict__ Stats,
    const float* __restrict__ bnws, const float* __restrict__ bnbs,
    const float* __restrict__ bnwv, float* __restrict__ Out){
  int idx = blockIdx.x*256 + threadIdx.x;
  if(idx >= NN*40) return;
  int n = idx/40, c = idx - n*40;
  float x = Pre[idx];
  float r;
  if(c < 16){
    float mu  = Stats[c]    * (1.f/NN);
    float var = Stats[16+c] * (1.f/NN) - mu*mu;
    r = (x - mu) / sqrtf(var + 1e-5f) * bnws[c] + bnbs[c];
  } else {
    int w = (c-16)/3;
    float n2 = Stats[32+w] * (1.f/NN);
    r = x / sqrtf(n2 + 1e-5f) * bnwv[w];
  }
  Out[idx] = r;
}

extern "C" void kernel_launch(void* const* d_in, const int* in_sizes, int n_in,
                              void* d_out, int out_size, void* d_ws, size_t ws_size,
                              hipStream_t stream){
  const float* frame = (const float*)d_in[0];
  const float* rot   = (const float*)d_in[1];
  const float* trans = (const float*)d_in[2];
  const float* tfn   = (const float*)d_in[3];
  const float* ef    = (const float*)d_in[4];
  const float* esh   = (const float*)d_in[5];
  const int*   ei    = (const int*)  d_in[6];
  const float* Wf0   = (const float*)d_in[7];
  const float* bf0   = (const float*)d_in[8];
  const float* Wf1   = (const float*)d_in[9];
  const float* bf1   = (const float*)d_in[10];
  const float* Wgs   = (const float*)d_in[11];
  const float* Wgv   = (const float*)d_in[12];
  const float* Wqs   = (const float*)d_in[13];
  const float* Wqv   = (const float*)d_in[14];
  const float* Wk1   = (const float*)d_in[15];
  const float* bk1   = (const float*)d_in[16];
  const float* Wk2   = (const float*)d_in[17];
  const float* bk2   = (const float*)d_in[18];
  const float* Wv1   = (const float*)d_in[19];
  const float* bv1   = (const float*)d_in[20];
  const float* Wv2   = (const float*)d_in[21];
  const float* bv2   = (const float*)d_in[22];
  const float* Wos   = (const float*)d_in[23];
  const float* Wov   = (const float*)d_in[24];
  const float* Wss   = (const float*)d_in[25];
  const float* Wsv   = (const float*)d_in[26];
  const float* bnws  = (const float*)d_in[27];
  const float* bnbs  = (const float*)d_in[28];
  const float* bnwv  = (const float*)d_in[29];

  float* ws   = (float*)d_ws;
  float* f0f1 = ws;                                   // N*160 (unused now)
  float* Gs   = f0f1 + (size_t)NN*160;                // N*16
  float* Gv   = Gs   + (size_t)NN*16;                 // N*24
  float* Qs   = Gv   + (size_t)NN*24;                 // N*16
  float* Qv   = Qs   + (size_t)NN*16;                 // N*24
  float* Attn = Qv   + (size_t)NN*24;                 // E*4
  float* Pre  = Attn + (size_t)EE*4;                  // N*40
  float* Upd  = Pre  + (size_t)NN*40;                 // N*64
  float* EdgeV= Upd  + (size_t)NN*64;                 // E*64
  float* Stats= EdgeV+ (size_t)EE*64;                 // 64 floats
  int*   cnt  = (int*)(Stats + 64);                   // N+16   (zeroed)
  int*   ofs  = cnt + (NN+16);                        // N+16 (use [0..N])
  int*   fill = ofs + (NN+16);                        // N+16
  int*   elist= fill + (NN+16);                       // E
  float* biasV= (float*)(elist + EE);                 // 896  (16B-aligned)
  float* biasK= biasV + 896;                          // 640
  unsigned short* A2rV = (unsigned short*)(biasK + 640);  // 896*32
  unsigned short* A2rK = A2rV + 896*32;                   // 640*32

  hipMemsetAsync(cnt, 0, (NN + 16)*sizeof(int), stream);

  k_node    <<<dim3(NN),              192, 0, stream>>>(frame, Wf0, bf0, Wf1, bf1,
                                                        rot, trans, tfn,
                                                        Wgs, Wgv, Wqs, Wqv,
                                                        Gs, Gv, Qs, Qv);
  k_prepw   <<<dim3(198),             256, 0, stream>>>(Wk2, bk2, Wv2, bv2, A2rK, A2rV, biasK, biasV);
  k_hist    <<<dim3((EE+255)/256),    256, 0, stream>>>(ei, cnt);
  k_scan    <<<dim3(1),               256, 0, stream>>>(cnt, ofs, fill);
  k_scatter <<<dim3((EE+255)/256),    256, 0, stream>>>(ei, fill, elist);
  k_edge_vk <<<dim3(2*NVB),           128, 0, stream>>>(ei, esh, ef, elist, Gs, Gv, Qs, Qv,
                                                        Wv1, bv1, Wk1, bk1,
                                                        A2rV, biasV, A2rK, biasK,
                                                        EdgeV, Attn);
  k_reduce  <<<dim3((NN+3)/4),        256, 0, stream>>>(ofs, Attn, EdgeV, Upd);
  k_nodeout <<<dim3((NN*40+255)/256), 256, 0, stream>>>(Upd, tfn, Wos, Wov, Wss, Wsv, Pre);
  k_stats   <<<dim3(24),              256, 0, stream>>>(Pre, Stats);
  k_final   <<<dim3((NN*40+255)/256), 256, 0, stream>>>(Pre, Stats, bnws, bnbs, bnwv, (float*)d_out);
}